// Round 1
// baseline (272.513 us; speedup 1.0000x reference)
//
#include <hip/hip_runtime.h>

#define B_ 2
#define T_ 2048
#define C_ 1024
#define H_ 16
#define D_ 64
// BT = 4096, N_qkv = 3072

using bf16x8 = __attribute__((ext_vector_type(8))) short;
using f32x4  = __attribute__((ext_vector_type(4))) float;

static __device__ __forceinline__ short f2bf(float f) {
  unsigned u = __builtin_bit_cast(unsigned, f);
  unsigned r = u + 0x7fffu + ((u >> 16) & 1u);
  return (short)(r >> 16);
}

// ---------------- cast f32 -> bf16 (vectorized) ----------------
__global__ __launch_bounds__(256) void cast_f32_bf16(const float* __restrict__ in,
                                                     short* __restrict__ out) {
  int i = blockIdx.x * blockDim.x + threadIdx.x;
  float4 v = ((const float4*)in)[i];
  short4 o;
  o.x = f2bf(v.x); o.y = f2bf(v.y); o.z = f2bf(v.z); o.w = f2bf(v.w);
  ((short4*)out)[i] = o;
}

// ---------------- transpose + cast: in [R][N] f32 -> out [N][R] bf16 ----------------
__global__ __launch_bounds__(256) void transpose_cast(const float* __restrict__ in,
                                                      short* __restrict__ out,
                                                      int R, int N) {
  __shared__ float tile[32][33];
  int bx = blockIdx.x * 32, by = blockIdx.y * 32;
  int tx = threadIdx.x, ty = threadIdx.y;
  #pragma unroll
  for (int j = 0; j < 32; j += 8)
    tile[ty + j][tx] = in[(size_t)(by + ty + j) * N + bx + tx];
  __syncthreads();
  #pragma unroll
  for (int j = 0; j < 32; j += 8)
    out[(size_t)(bx + ty + j) * R + by + tx] = f2bf(tile[tx][ty + j]);
}

// ---------------- GEMM core macro-shared pieces ----------------
// A: [M][1024] bf16 row-major. Bt: [N][1024] bf16 (i.e. B^T, k-contiguous).
// 128x128 tile, BK=32, 4 waves (2x2), each wave 64x64 via 4x4 16x16x32 MFMA frags.
// LDS layout: row*32 + (chunk ^ ((row>>1)&3))*8 + (k&7)   (16B-aligned, conflict-free)

__global__ __launch_bounds__(256) void gemm_qkv(const short* __restrict__ A,
                                                const short* __restrict__ Bt,
                                                const float* __restrict__ bias,
                                                short* __restrict__ Qo,
                                                short* __restrict__ Ko,
                                                short* __restrict__ Vo) {
  __shared__ short sA[128 * 32];
  __shared__ short sB[128 * 32];
  const int tid = threadIdx.x;
  const int w = tid >> 6, lane = tid & 63;
  const int wm = w >> 1, wn = w & 1;
  const int g = lane >> 4, r16 = lane & 15;
  const int m0 = blockIdx.x * 128, n0 = blockIdx.y * 128;
  const int arow = tid >> 2, ac = tid & 3;

  f32x4 acc[4][4] = {};

  for (int k0 = 0; k0 < 1024; k0 += 32) {
    __syncthreads();
    #pragma unroll
    for (int h = 0; h < 2; ++h) {
      int row = arow + h * 64;
      int c = ac ^ ((row >> 1) & 3);
      int4 va = *(const int4*)&A[(size_t)(m0 + row) * 1024 + k0 + ac * 8];
      *(int4*)&sA[row * 32 + c * 8] = va;
      int4 vb = *(const int4*)&Bt[(size_t)(n0 + row) * 1024 + k0 + ac * 8];
      *(int4*)&sB[row * 32 + c * 8] = vb;
    }
    __syncthreads();
    bf16x8 af[4], bf[4];
    #pragma unroll
    for (int mi = 0; mi < 4; ++mi) {
      int row = wm * 64 + mi * 16 + r16;
      af[mi] = *(const bf16x8*)&sA[row * 32 + ((g ^ ((row >> 1) & 3)) * 8)];
    }
    #pragma unroll
    for (int ni = 0; ni < 4; ++ni) {
      int row = wn * 64 + ni * 16 + r16;
      bf[ni] = *(const bf16x8*)&sB[row * 32 + ((g ^ ((row >> 1) & 3)) * 8)];
    }
    #pragma unroll
    for (int mi = 0; mi < 4; ++mi)
      #pragma unroll
      for (int ni = 0; ni < 4; ++ni)
        acc[mi][ni] = __builtin_amdgcn_mfma_f32_16x16x32_bf16(af[mi], bf[ni], acc[mi][ni], 0, 0, 0);
  }

  // epilogue: scatter into Q/K/V [B][H][T][D] bf16 with bias
  #pragma unroll
  for (int mi = 0; mi < 4; ++mi) {
    #pragma unroll
    for (int ni = 0; ni < 4; ++ni) {
      int n = n0 + wn * 64 + ni * 16 + r16;
      float bv = bias[n];
      int which = n >> 10;
      int c = n & 1023;
      int hh = c >> 6, d = c & 63;
      short* dst = (which == 0) ? Qo : ((which == 1) ? Ko : Vo);
      #pragma unroll
      for (int rr = 0; rr < 4; ++rr) {
        int m = m0 + wm * 64 + mi * 16 + g * 4 + rr;
        int b = m >> 11, t = m & 2047;
        float v = acc[mi][ni][rr] + bv;
        dst[(size_t)((b * H_ + hh) * T_ + t) * D_ + d] = f2bf(v);
      }
    }
  }
}

__global__ __launch_bounds__(256) void gemm_out(const short* __restrict__ A,
                                                const short* __restrict__ Bt,
                                                const float* __restrict__ bias,
                                                float* __restrict__ Out) {
  __shared__ short sA[128 * 32];
  __shared__ short sB[128 * 32];
  const int tid = threadIdx.x;
  const int w = tid >> 6, lane = tid & 63;
  const int wm = w >> 1, wn = w & 1;
  const int g = lane >> 4, r16 = lane & 15;
  const int m0 = blockIdx.x * 128, n0 = blockIdx.y * 128;
  const int arow = tid >> 2, ac = tid & 3;

  f32x4 acc[4][4] = {};

  for (int k0 = 0; k0 < 1024; k0 += 32) {
    __syncthreads();
    #pragma unroll
    for (int h = 0; h < 2; ++h) {
      int row = arow + h * 64;
      int c = ac ^ ((row >> 1) & 3);
      int4 va = *(const int4*)&A[(size_t)(m0 + row) * 1024 + k0 + ac * 8];
      *(int4*)&sA[row * 32 + c * 8] = va;
      int4 vb = *(const int4*)&Bt[(size_t)(n0 + row) * 1024 + k0 + ac * 8];
      *(int4*)&sB[row * 32 + c * 8] = vb;
    }
    __syncthreads();
    bf16x8 af[4], bf[4];
    #pragma unroll
    for (int mi = 0; mi < 4; ++mi) {
      int row = wm * 64 + mi * 16 + r16;
      af[mi] = *(const bf16x8*)&sA[row * 32 + ((g ^ ((row >> 1) & 3)) * 8)];
    }
    #pragma unroll
    for (int ni = 0; ni < 4; ++ni) {
      int row = wn * 64 + ni * 16 + r16;
      bf[ni] = *(const bf16x8*)&sB[row * 32 + ((g ^ ((row >> 1) & 3)) * 8)];
    }
    #pragma unroll
    for (int mi = 0; mi < 4; ++mi)
      #pragma unroll
      for (int ni = 0; ni < 4; ++ni)
        acc[mi][ni] = __builtin_amdgcn_mfma_f32_16x16x32_bf16(af[mi], bf[ni], acc[mi][ni], 0, 0, 0);
  }

  #pragma unroll
  for (int mi = 0; mi < 4; ++mi) {
    #pragma unroll
    for (int ni = 0; ni < 4; ++ni) {
      int n = n0 + wn * 64 + ni * 16 + r16;
      float bv = bias[n];
      #pragma unroll
      for (int rr = 0; rr < 4; ++rr) {
        int m = m0 + wm * 64 + mi * 16 + g * 4 + rr;
        Out[(size_t)m * 1024 + n] = acc[mi][ni][rr] + bv;
      }
    }
  }
}

// ---------------- flash attention ----------------
// grid (T/64, B*H), 256 threads = 4 waves; wave w owns q rows q0+w*16 .. +15.
// K read direct from global (L2-resident). V staged transposed in LDS.
// P re-fragmented through per-wave swizzled LDS.
__global__ __launch_bounds__(256) void attn_fwd(const short* __restrict__ Q,
                                                const short* __restrict__ K,
                                                const short* __restrict__ V,
                                                short* __restrict__ O) {
  __shared__ short vT[64 * 36];      // V^T tile [d][key], pad-36 rows
  __shared__ short pl[4 * 16 * 32];  // per-wave P, chunk-swizzled

  const int tid = threadIdx.x;
  const int w = tid >> 6, lane = tid & 63;
  const int g = lane >> 4, r16 = lane & 15;
  const int q0 = blockIdx.x * 64;
  const int bh = blockIdx.y;

  const short* Qh = Q + (size_t)bh * T_ * D_;
  const short* Kh = K + (size_t)bh * T_ * D_;
  const short* Vh = V + (size_t)bh * T_ * D_;

  // Q fragments (A-frag): row = lane%16, k = s*32 + 8*(lane>>4) + j
  const int qrow_a = q0 + w * 16 + r16;
  bf16x8 qf[2];
  qf[0] = *(const bf16x8*)&Qh[(size_t)qrow_a * 64 + g * 8];
  qf[1] = *(const bf16x8*)&Qh[(size_t)qrow_a * 64 + 32 + g * 8];

  f32x4 o[4] = {};
  float mrow[4], lrow[4];
  #pragma unroll
  for (int r = 0; r < 4; ++r) { mrow[r] = -1e30f; lrow[r] = 0.f; }

  const int vkey = tid >> 3;        // 0..31
  const int vd0 = (tid & 7) * 8;    // 0..56

  const int ktiles = (q0 + 63) / 32 + 1;
  for (int kt = 0; kt < ktiles; ++kt) {
    const int k0 = kt * 32;
    __syncthreads();  // protect vT from previous iteration's readers

    // stage V^T: thread loads V[k0+vkey][vd0..vd0+7], scatters to vT[d][key]
    int4 vv = *(const int4*)&Vh[(size_t)(k0 + vkey) * 64 + vd0];
    const short* vs = (const short*)&vv;
    #pragma unroll
    for (int j = 0; j < 8; ++j)
      vT[(vd0 + j) * 36 + vkey] = vs[j];

    // S = Q K^T  (B-frag from global K: col=key=lane%16, k=d contiguous)
    f32x4 s[2] = {};
    #pragma unroll
    for (int nt = 0; nt < 2; ++nt) {
      bf16x8 kf0 = *(const bf16x8*)&Kh[(size_t)(k0 + nt * 16 + r16) * 64 + g * 8];
      bf16x8 kf1 = *(const bf16x8*)&Kh[(size_t)(k0 + nt * 16 + r16) * 64 + 32 + g * 8];
      s[nt] = __builtin_amdgcn_mfma_f32_16x16x32_bf16(qf[0], kf0, s[nt], 0, 0, 0);
      s[nt] = __builtin_amdgcn_mfma_f32_16x16x32_bf16(qf[1], kf1, s[nt], 0, 0, 0);
    }

    // online softmax per q-row (rows = g*4+r, cols = key across 16 lanes)
    #pragma unroll
    for (int r = 0; r < 4; ++r) {
      int qrow = q0 + w * 16 + g * 4 + r;
      float v0 = s[0][r] * 0.125f;
      float v1 = s[1][r] * 0.125f;
      if (k0 + r16 > qrow)       v0 = -1e30f;
      if (k0 + 16 + r16 > qrow)  v1 = -1e30f;
      float mx = fmaxf(v0, v1);
      mx = fmaxf(mx, __shfl_xor(mx, 1));
      mx = fmaxf(mx, __shfl_xor(mx, 2));
      mx = fmaxf(mx, __shfl_xor(mx, 4));
      mx = fmaxf(mx, __shfl_xor(mx, 8));
      float mn = fmaxf(mrow[r], mx);
      float alpha = __expf(mrow[r] - mn);
      mrow[r] = mn;
      float p0 = __expf(v0 - mn);
      float p1 = __expf(v1 - mn);
      float rs = p0 + p1;
      rs += __shfl_xor(rs, 1);
      rs += __shfl_xor(rs, 2);
      rs += __shfl_xor(rs, 4);
      rs += __shfl_xor(rs, 8);
      lrow[r] = lrow[r] * alpha + rs;
      o[0][r] *= alpha; o[1][r] *= alpha; o[2][r] *= alpha; o[3][r] *= alpha;

      // write P (bf16) into per-wave swizzled LDS
      int row_w = g * 4 + r;
      int sw = (row_w >> 1) & 3;
      pl[w * 512 + row_w * 32 + (((r16 >> 3) ^ sw) * 8) + (r16 & 7)] = f2bf(p0);
      pl[w * 512 + row_w * 32 + ((((16 + r16) >> 3) ^ sw) * 8) + (r16 & 7)] = f2bf(p1);
    }

    // re-fragment P as A-frag: row = lane%16, k = 8*(lane>>4)+j
    bf16x8 pa = *(const bf16x8*)&pl[w * 512 + r16 * 32 + ((g ^ ((r16 >> 1) & 3)) * 8)];

    __syncthreads();  // vT writes visible

    // O += P @ V   (B-frag from vT: col=d=lane%16, k=key contiguous)
    #pragma unroll
    for (int nt = 0; nt < 4; ++nt) {
      int d = nt * 16 + r16;
      const short* vp = &vT[d * 36 + g * 8];
      short4 a = *(const short4*)vp;
      short4 b2 = *(const short4*)(vp + 4);
      bf16x8 vb = {a.x, a.y, a.z, a.w, b2.x, b2.y, b2.z, b2.w};
      o[nt] = __builtin_amdgcn_mfma_f32_16x16x32_bf16(pa, vb, o[nt], 0, 0, 0);
    }
  }

  // epilogue: O /= l, store bf16 [B][T][C] with c = h*64+d
  const int b = bh >> 4, hh = bh & 15;
  #pragma unroll
  for (int nt = 0; nt < 4; ++nt) {
    int d = nt * 16 + r16;
    #pragma unroll
    for (int r = 0; r < 4; ++r) {
      int t = q0 + w * 16 + g * 4 + r;
      float val = o[nt][r] / lrow[r];
      O[(size_t)(b * T_ + t) * C_ + hh * 64 + d] = f2bf(val);
    }
  }
}

extern "C" void kernel_launch(void* const* d_in, const int* in_sizes, int n_in,
                              void* d_out, int out_size, void* d_ws, size_t ws_size,
                              hipStream_t stream) {
  const float* x     = (const float*)d_in[0];
  const float* w_qkv = (const float*)d_in[1];
  const float* b_qkv = (const float*)d_in[2];
  const float* w_out = (const float*)d_in[3];
  const float* b_out = (const float*)d_in[4];
  float* out = (float*)d_out;

  char* ws = (char*)d_ws;
  if (ws_size < (size_t)(40u << 20)) return;  // need 40 MiB

  short* xb     = (short*)(ws);                        // 8 MiB  [4096][1024] bf16
  short* wqkvT  = (short*)(ws + ((size_t)8u << 20));   // 6 MiB  [3072][1024] bf16
  short* woutT  = (short*)(ws + ((size_t)14u << 20));  // 2 MiB  [1024][1024] bf16
  short* Qb     = (short*)(ws + ((size_t)16u << 20));  // 8 MiB  [B][H][T][D]
  short* Kb     = (short*)(ws + ((size_t)24u << 20));  // 8 MiB
  short* Vb     = (short*)(ws + ((size_t)32u << 20));  // 8 MiB
  short* attn_o = xb;  // reuse: xb dead after gemm_qkv

  // 1. cast x -> bf16 (4194304 elems / 4 per thread)
  cast_f32_bf16<<<4096, 256, 0, stream>>>(x, xb);
  // 2. transpose-cast weights to [N][K] bf16
  transpose_cast<<<dim3(96, 32), dim3(32, 8), 0, stream>>>(w_qkv, wqkvT, 1024, 3072);
  transpose_cast<<<dim3(32, 32), dim3(32, 8), 0, stream>>>(w_out, woutT, 1024, 1024);
  // 3. QKV projection -> Q/K/V [B][H][T][D] bf16
  gemm_qkv<<<dim3(32, 24), 256, 0, stream>>>(xb, wqkvT, b_qkv, Qb, Kb, Vb);
  // 4. causal flash attention -> attn_o [B][T][C] bf16
  attn_fwd<<<dim3(32, 32), 256, 0, stream>>>(Qb, Kb, Vb, attn_o);
  // 5. output projection -> f32 out
  gemm_out<<<dim3(32, 8), 256, 0, stream>>>(attn_o, woutT, b_out, out);
}

// Round 2
// 157.530 us; speedup vs baseline: 1.7299x; 1.7299x over previous
//
#include <hip/hip_runtime.h>

#define B_ 2
#define T_ 2048
#define C_ 1024
#define H_ 16
#define D_ 64

using bf16x8 = __attribute__((ext_vector_type(8))) short;
using f32x4  = __attribute__((ext_vector_type(4))) float;

static __device__ __forceinline__ short f2bf(float f) {
  unsigned u = __builtin_bit_cast(unsigned, f);
  unsigned r = u + 0x7fffu + ((u >> 16) & 1u);
  return (short)(r >> 16);
}

static __device__ __forceinline__ int kchunk_of(int nt, int r16) {
  return nt * 2 + (r16 >> 3);  // k-chunk of key nt*16+r16 within a 64-key tile
}

#define GLD16(gp, lp) __builtin_amdgcn_global_load_lds( \
    (const __attribute__((address_space(1))) void*)(gp), \
    (__attribute__((address_space(3))) void*)(lp), 16, 0, 0)

// ---------------- cast f32 -> bf16 (vectorized) ----------------
__global__ __launch_bounds__(256) void cast_f32_bf16(const float* __restrict__ in,
                                                     short* __restrict__ out) {
  int i = blockIdx.x * blockDim.x + threadIdx.x;
  float4 v = ((const float4*)in)[i];
  short4 o;
  o.x = f2bf(v.x); o.y = f2bf(v.y); o.z = f2bf(v.z); o.w = f2bf(v.w);
  ((short4*)out)[i] = o;
}

// ---------------- transpose + cast: in [R][N] f32 -> out [N][R] bf16 ----------------
__global__ __launch_bounds__(256) void transpose_cast(const float* __restrict__ in,
                                                      short* __restrict__ out,
                                                      int R, int N) {
  __shared__ float tile[32][33];
  int bx = blockIdx.x * 32, by = blockIdx.y * 32;
  int tx = threadIdx.x, ty = threadIdx.y;
  #pragma unroll
  for (int j = 0; j < 32; j += 8)
    tile[ty + j][tx] = in[(size_t)(by + ty + j) * N + bx + tx];
  __syncthreads();
  #pragma unroll
  for (int j = 0; j < 32; j += 8)
    out[(size_t)(bx + ty + j) * R + by + tx] = f2bf(tile[tx][ty + j]);
}

// ---------------- GEMM: 128x128 tile, BK=32, 4 waves, global_load_lds staging ----------------
__global__ __launch_bounds__(256) void gemm_qkv(const short* __restrict__ A,
                                                const short* __restrict__ Bt,
                                                const float* __restrict__ bias,
                                                short* __restrict__ Qo,
                                                short* __restrict__ Ko,
                                                short* __restrict__ Vo) {
  __shared__ short sA[128 * 32];
  __shared__ short sB[128 * 32];
  const int tid = threadIdx.x;
  const int w = tid >> 6, lane = tid & 63;
  const int wm = w >> 1, wn = w & 1;
  const int g = lane >> 4, r16 = lane & 15;
  const int m0 = blockIdx.x * 128, n0 = blockIdx.y * 128;
  const int lrow = lane >> 2, slot = lane & 3;

  f32x4 acc[4][4] = {};

  for (int k0 = 0; k0 < 1024; k0 += 32) {
    __syncthreads();
    #pragma unroll
    for (int h = 0; h < 2; ++h) {
      int rbase = h * 64 + w * 16;
      int row = rbase + lrow;
      int sw = (row >> 1) & 3;
      GLD16(&A[(size_t)(m0 + row) * 1024 + k0 + ((slot ^ sw) * 8)], &sA[rbase * 32]);
      GLD16(&Bt[(size_t)(n0 + row) * 1024 + k0 + ((slot ^ sw) * 8)], &sB[rbase * 32]);
    }
    __syncthreads();
    bf16x8 af[4], bf[4];
    #pragma unroll
    for (int mi = 0; mi < 4; ++mi) {
      int row = wm * 64 + mi * 16 + r16;
      af[mi] = *(const bf16x8*)&sA[row * 32 + ((g ^ ((row >> 1) & 3)) * 8)];
    }
    #pragma unroll
    for (int ni = 0; ni < 4; ++ni) {
      int row = wn * 64 + ni * 16 + r16;
      bf[ni] = *(const bf16x8*)&sB[row * 32 + ((g ^ ((row >> 1) & 3)) * 8)];
    }
    #pragma unroll
    for (int mi = 0; mi < 4; ++mi)
      #pragma unroll
      for (int ni = 0; ni < 4; ++ni)
        acc[mi][ni] = __builtin_amdgcn_mfma_f32_16x16x32_bf16(af[mi], bf[ni], acc[mi][ni], 0, 0, 0);
  }

  #pragma unroll
  for (int mi = 0; mi < 4; ++mi) {
    #pragma unroll
    for (int ni = 0; ni < 4; ++ni) {
      int n = n0 + wn * 64 + ni * 16 + r16;
      float bv = bias[n];
      int which = n >> 10;
      int c = n & 1023;
      int hh = c >> 6, d = c & 63;
      short* dst = (which == 0) ? Qo : ((which == 1) ? Ko : Vo);
      #pragma unroll
      for (int rr = 0; rr < 4; ++rr) {
        int m = m0 + wm * 64 + mi * 16 + g * 4 + rr;
        int b = m >> 11, t = m & 2047;
        dst[(size_t)((b * H_ + hh) * T_ + t) * D_ + d] = f2bf(acc[mi][ni][rr] + bv);
      }
    }
  }
}

__global__ __launch_bounds__(256) void gemm_out(const short* __restrict__ A,
                                                const short* __restrict__ Bt,
                                                const float* __restrict__ bias,
                                                float* __restrict__ Out) {
  __shared__ short sA[128 * 32];
  __shared__ short sB[128 * 32];
  const int tid = threadIdx.x;
  const int w = tid >> 6, lane = tid & 63;
  const int wm = w >> 1, wn = w & 1;
  const int g = lane >> 4, r16 = lane & 15;
  const int m0 = blockIdx.x * 128, n0 = blockIdx.y * 128;
  const int lrow = lane >> 2, slot = lane & 3;

  f32x4 acc[4][4] = {};

  for (int k0 = 0; k0 < 1024; k0 += 32) {
    __syncthreads();
    #pragma unroll
    for (int h = 0; h < 2; ++h) {
      int rbase = h * 64 + w * 16;
      int row = rbase + lrow;
      int sw = (row >> 1) & 3;
      GLD16(&A[(size_t)(m0 + row) * 1024 + k0 + ((slot ^ sw) * 8)], &sA[rbase * 32]);
      GLD16(&Bt[(size_t)(n0 + row) * 1024 + k0 + ((slot ^ sw) * 8)], &sB[rbase * 32]);
    }
    __syncthreads();
    bf16x8 af[4], bf[4];
    #pragma unroll
    for (int mi = 0; mi < 4; ++mi) {
      int row = wm * 64 + mi * 16 + r16;
      af[mi] = *(const bf16x8*)&sA[row * 32 + ((g ^ ((row >> 1) & 3)) * 8)];
    }
    #pragma unroll
    for (int ni = 0; ni < 4; ++ni) {
      int row = wn * 64 + ni * 16 + r16;
      bf[ni] = *(const bf16x8*)&sB[row * 32 + ((g ^ ((row >> 1) & 3)) * 8)];
    }
    #pragma unroll
    for (int mi = 0; mi < 4; ++mi)
      #pragma unroll
      for (int ni = 0; ni < 4; ++ni)
        acc[mi][ni] = __builtin_amdgcn_mfma_f32_16x16x32_bf16(af[mi], bf[ni], acc[mi][ni], 0, 0, 0);
  }

  #pragma unroll
  for (int mi = 0; mi < 4; ++mi) {
    #pragma unroll
    for (int ni = 0; ni < 4; ++ni) {
      int n = n0 + wn * 64 + ni * 16 + r16;
      float bv = bias[n];
      #pragma unroll
      for (int rr = 0; rr < 4; ++rr) {
        int m = m0 + wm * 64 + mi * 16 + g * 4 + rr;
        Out[(size_t)m * 1024 + n] = acc[mi][ni][rr] + bv;
      }
    }
  }
}

// ---------------- flash attention (paired q-tiles, KVBLK=64) ----------------
__global__ __launch_bounds__(256) void attn_fwd(const short* __restrict__ Q,
                                                const short* __restrict__ K,
                                                const short* __restrict__ V,
                                                short* __restrict__ O) {
  __shared__ short sK[64 * 64];     // [key][d], slot c holds d-chunk c^(key&7)
  __shared__ short vT[64 * 64];     // [d][key], slot c holds k-chunk c^(d&7)
  __shared__ short pl[4 * 16 * 64]; // per-wave P [row][key], slot c holds k-chunk c^(row&7)

  const int tid = threadIdx.x;
  const int w = tid >> 6, lane = tid & 63;
  const int g = lane >> 4, r16 = lane & 15;
  const int bh = blockIdx.x;
  const int b = bh >> 4, hh = bh & 15;

  const short* Qh = Q + (size_t)bh * T_ * D_;
  const short* Kh = K + (size_t)bh * T_ * D_;
  const short* Vh = V + (size_t)bh * T_ * D_;
  short* pw = &pl[w * 16 * 64];

  const int krow_in_wave = lane >> 3;
  const int kslot = lane & 7;
  const int kp = tid & 31;     // V staging: key pair index
  const int vd0 = (tid >> 5) * 8;

  for (int half = 0; half < 2; ++half) {
    const int qi = half ? (31 - (int)blockIdx.y) : (int)blockIdx.y;
    const int q0 = qi * 64;
    const int qrow_a = q0 + w * 16 + r16;
    bf16x8 qf[2];
    qf[0] = *(const bf16x8*)&Qh[(size_t)qrow_a * 64 + g * 8];
    qf[1] = *(const bf16x8*)&Qh[(size_t)qrow_a * 64 + 32 + g * 8];

    f32x4 o[4] = {};
    float mrow[4], lsum[4];
    #pragma unroll
    for (int r = 0; r < 4; ++r) { mrow[r] = -1e30f; lsum[r] = 0.f; }

    for (int kt = 0; kt <= qi; ++kt) {
      const int k0 = kt * 64;
      __syncthreads();

      #pragma unroll
      for (int p = 0; p < 2; ++p) {
        int row = w * 16 + p * 8 + krow_in_wave;
        GLD16(&Kh[(size_t)(k0 + row) * 64 + ((kslot ^ (row & 7)) * 8)],
              &sK[(w * 16 + p * 8) * 64]);
      }
      {
        int4 v0 = *(const int4*)&Vh[(size_t)(k0 + 2 * kp) * 64 + vd0];
        int4 v1 = *(const int4*)&Vh[(size_t)(k0 + 2 * kp + 1) * 64 + vd0];
        const short* a0 = (const short*)&v0;
        const short* a1 = (const short*)&v1;
        int ch = kp >> 2;
        int e = (kp & 3) * 2;
        #pragma unroll
        for (int j = 0; j < 8; ++j) {
          int d = vd0 + j;  // d&7 == j
          int val = ((int)(unsigned short)a0[j]) | (((int)(unsigned short)a1[j]) << 16);
          *(int*)&vT[d * 64 + ((ch ^ j) * 8) + e] = val;
        }
      }
      __syncthreads();

      f32x4 s[4] = {};
      #pragma unroll
      for (int nt = 0; nt < 4; ++nt) {
        int row = nt * 16 + r16;
        #pragma unroll
        for (int c = 0; c < 2; ++c) {
          bf16x8 kf = *(const bf16x8*)&sK[row * 64 + (((c * 4 + g) ^ (row & 7)) * 8)];
          s[nt] = __builtin_amdgcn_mfma_f32_16x16x32_bf16(qf[c], kf, s[nt], 0, 0, 0);
        }
      }

      const bool diag = (kt == qi);
      #pragma unroll
      for (int r = 0; r < 4; ++r) {
        int qrow = q0 + w * 16 + g * 4 + r;
        float v[4];
        #pragma unroll
        for (int nt = 0; nt < 4; ++nt) {
          v[nt] = s[nt][r] * 0.125f;
          if (diag && (k0 + nt * 16 + r16 > qrow)) v[nt] = -1e30f;
        }
        float mx = fmaxf(fmaxf(v[0], v[1]), fmaxf(v[2], v[3]));
        mx = fmaxf(mx, __shfl_xor(mx, 1));
        mx = fmaxf(mx, __shfl_xor(mx, 2));
        mx = fmaxf(mx, __shfl_xor(mx, 4));
        mx = fmaxf(mx, __shfl_xor(mx, 8));
        float mn = fmaxf(mrow[r], mx);
        float alpha = __expf(mrow[r] - mn);
        mrow[r] = mn;
        float p0 = __expf(v[0] - mn), p1 = __expf(v[1] - mn),
              p2 = __expf(v[2] - mn), p3 = __expf(v[3] - mn);
        float rs = (p0 + p1) + (p2 + p3);
        rs += __shfl_xor(rs, 1);
        rs += __shfl_xor(rs, 2);
        rs += __shfl_xor(rs, 4);
        rs += __shfl_xor(rs, 8);
        lsum[r] = lsum[r] * alpha + rs;
        o[0][r] *= alpha; o[1][r] *= alpha; o[2][r] *= alpha; o[3][r] *= alpha;

        int rw = g * 4 + r;
        int sw = rw & 7;
        int e = r16 & 7;
        pw[rw * 64 + ((kchunk_of(0, r16) ^ sw) * 8) + e] = f2bf(p0);
        pw[rw * 64 + ((kchunk_of(1, r16) ^ sw) * 8) + e] = f2bf(p1);
        pw[rw * 64 + ((kchunk_of(2, r16) ^ sw) * 8) + e] = f2bf(p2);
        pw[rw * 64 + ((kchunk_of(3, r16) ^ sw) * 8) + e] = f2bf(p3);
      }

      bf16x8 pa0 = *(const bf16x8*)&pw[r16 * 64 + ((g ^ (r16 & 7)) * 8)];
      bf16x8 pa1 = *(const bf16x8*)&pw[r16 * 64 + (((4 + g) ^ (r16 & 7)) * 8)];
      #pragma unroll
      for (int nt = 0; nt < 4; ++nt) {
        int d = nt * 16 + r16;
        bf16x8 vb0 = *(const bf16x8*)&vT[d * 64 + ((g ^ (d & 7)) * 8)];
        bf16x8 vb1 = *(const bf16x8*)&vT[d * 64 + (((4 + g) ^ (d & 7)) * 8)];
        o[nt] = __builtin_amdgcn_mfma_f32_16x16x32_bf16(pa0, vb0, o[nt], 0, 0, 0);
        o[nt] = __builtin_amdgcn_mfma_f32_16x16x32_bf16(pa1, vb1, o[nt], 0, 0, 0);
      }
    }

    #pragma unroll
    for (int nt = 0; nt < 4; ++nt) {
      int d = nt * 16 + r16;
      #pragma unroll
      for (int r = 0; r < 4; ++r) {
        int t = q0 + w * 16 + g * 4 + r;
        O[(size_t)(b * T_ + t) * C_ + hh * 64 + d] = f2bf(o[nt][r] / lsum[r]);
      }
    }
  }
}

extern "C" void kernel_launch(void* const* d_in, const int* in_sizes, int n_in,
                              void* d_out, int out_size, void* d_ws, size_t ws_size,
                              hipStream_t stream) {
  const float* x     = (const float*)d_in[0];
  const float* w_qkv = (const float*)d_in[1];
  const float* b_qkv = (const float*)d_in[2];
  const float* w_out = (const float*)d_in[3];
  const float* b_out = (const float*)d_in[4];
  float* out = (float*)d_out;

  char* ws = (char*)d_ws;
  if (ws_size < (size_t)(40u << 20)) return;

  short* xb     = (short*)(ws);                        // 8 MiB  [4096][1024] bf16
  short* wqkvT  = (short*)(ws + ((size_t)8u << 20));   // 6 MiB  [3072][1024] bf16
  short* woutT  = (short*)(ws + ((size_t)14u << 20));  // 2 MiB  [1024][1024] bf16
  short* Qb     = (short*)(ws + ((size_t)16u << 20));  // 8 MiB  [B][H][T][D]
  short* Kb     = (short*)(ws + ((size_t)24u << 20));  // 8 MiB
  short* Vb     = (short*)(ws + ((size_t)32u << 20));  // 8 MiB
  short* attn_o = xb;  // xb dead after gemm_qkv

  cast_f32_bf16<<<4096, 256, 0, stream>>>(x, xb);
  transpose_cast<<<dim3(96, 32), dim3(32, 8), 0, stream>>>(w_qkv, wqkvT, 1024, 3072);
  transpose_cast<<<dim3(32, 32), dim3(32, 8), 0, stream>>>(w_out, woutT, 1024, 1024);
  gemm_qkv<<<dim3(32, 24), 256, 0, stream>>>(xb, wqkvT, b_qkv, Qb, Kb, Vb);
  attn_fwd<<<dim3(32, 16), 256, 0, stream>>>(Qb, Kb, Vb, attn_o);
  gemm_out<<<dim3(32, 8), 256, 0, stream>>>(attn_o, woutT, b_out, out);
}

// Round 3
// 153.141 us; speedup vs baseline: 1.7795x; 1.0287x over previous
//
#include <hip/hip_runtime.h>

#define B_ 2
#define T_ 2048
#define C_ 1024
#define H_ 16
#define D_ 64

using bf16x8 = __attribute__((ext_vector_type(8))) short;
using f32x4  = __attribute__((ext_vector_type(4))) float;

static __device__ __forceinline__ short f2bf(float f) {
  unsigned u = __builtin_bit_cast(unsigned, f);
  unsigned r = u + 0x7fffu + ((u >> 16) & 1u);
  return (short)(r >> 16);
}

static __device__ __forceinline__ int kchunk_of(int nt, int r16) {
  return nt * 2 + (r16 >> 3);  // k-chunk of key nt*16+r16 within a 64-key tile
}

#define GLD16(gp, lp) __builtin_amdgcn_global_load_lds( \
    (const __attribute__((address_space(1))) void*)(gp), \
    (__attribute__((address_space(3))) void*)(lp), 16, 0, 0)

// ---------------- cast f32 -> bf16 (vectorized) ----------------
__global__ __launch_bounds__(256) void cast_f32_bf16(const float* __restrict__ in,
                                                     short* __restrict__ out) {
  int i = blockIdx.x * blockDim.x + threadIdx.x;
  float4 v = ((const float4*)in)[i];
  short4 o;
  o.x = f2bf(v.x); o.y = f2bf(v.y); o.z = f2bf(v.z); o.w = f2bf(v.w);
  ((short4*)out)[i] = o;
}

// ---------------- transpose + cast: in [R][N] f32 -> out [N][R] bf16 ----------------
__global__ __launch_bounds__(256) void transpose_cast(const float* __restrict__ in,
                                                      short* __restrict__ out,
                                                      int R, int N) {
  __shared__ float tile[32][33];
  int bx = blockIdx.x * 32, by = blockIdx.y * 32;
  int tx = threadIdx.x, ty = threadIdx.y;
  #pragma unroll
  for (int j = 0; j < 32; j += 8)
    tile[ty + j][tx] = in[(size_t)(by + ty + j) * N + bx + tx];
  __syncthreads();
  #pragma unroll
  for (int j = 0; j < 32; j += 8)
    out[(size_t)(bx + ty + j) * R + by + tx] = f2bf(tile[tx][ty + j]);
}

// ---------------- GEMM: 128x128 tile, BK=32, 4 waves, global_load_lds staging ----------------
__global__ __launch_bounds__(256) void gemm_qkv(const short* __restrict__ A,
                                                const short* __restrict__ Bt,
                                                const float* __restrict__ bias,
                                                short* __restrict__ Qo,
                                                short* __restrict__ Ko,
                                                short* __restrict__ Vo) {
  __shared__ short sA[128 * 32];
  __shared__ short sB[128 * 32];
  const int tid = threadIdx.x;
  const int w = tid >> 6, lane = tid & 63;
  const int wm = w >> 1, wn = w & 1;
  const int g = lane >> 4, r16 = lane & 15;
  const int m0 = blockIdx.x * 128, n0 = blockIdx.y * 128;
  const int lrow = lane >> 2, slot = lane & 3;

  f32x4 acc[4][4] = {};

  for (int k0 = 0; k0 < 1024; k0 += 32) {
    __syncthreads();
    #pragma unroll
    for (int h = 0; h < 2; ++h) {
      int rbase = h * 64 + w * 16;
      int row = rbase + lrow;
      int sw = (row >> 1) & 3;
      GLD16(&A[(size_t)(m0 + row) * 1024 + k0 + ((slot ^ sw) * 8)], &sA[rbase * 32]);
      GLD16(&Bt[(size_t)(n0 + row) * 1024 + k0 + ((slot ^ sw) * 8)], &sB[rbase * 32]);
    }
    __syncthreads();
    bf16x8 af[4], bf[4];
    #pragma unroll
    for (int mi = 0; mi < 4; ++mi) {
      int row = wm * 64 + mi * 16 + r16;
      af[mi] = *(const bf16x8*)&sA[row * 32 + ((g ^ ((row >> 1) & 3)) * 8)];
    }
    #pragma unroll
    for (int ni = 0; ni < 4; ++ni) {
      int row = wn * 64 + ni * 16 + r16;
      bf[ni] = *(const bf16x8*)&sB[row * 32 + ((g ^ ((row >> 1) & 3)) * 8)];
    }
    #pragma unroll
    for (int mi = 0; mi < 4; ++mi)
      #pragma unroll
      for (int ni = 0; ni < 4; ++ni)
        acc[mi][ni] = __builtin_amdgcn_mfma_f32_16x16x32_bf16(af[mi], bf[ni], acc[mi][ni], 0, 0, 0);
  }

  #pragma unroll
  for (int mi = 0; mi < 4; ++mi) {
    #pragma unroll
    for (int ni = 0; ni < 4; ++ni) {
      int n = n0 + wn * 64 + ni * 16 + r16;
      float bv = bias[n];
      int which = n >> 10;
      int c = n & 1023;
      int hh = c >> 6, d = c & 63;
      short* dst = (which == 0) ? Qo : ((which == 1) ? Ko : Vo);
      #pragma unroll
      for (int rr = 0; rr < 4; ++rr) {
        int m = m0 + wm * 64 + mi * 16 + g * 4 + rr;
        int b = m >> 11, t = m & 2047;
        dst[(size_t)((b * H_ + hh) * T_ + t) * D_ + d] = f2bf(acc[mi][ni][rr] + bv);
      }
    }
  }
}

__global__ __launch_bounds__(256) void gemm_out(const short* __restrict__ A,
                                                const short* __restrict__ Bt,
                                                const float* __restrict__ bias,
                                                float* __restrict__ Out) {
  __shared__ short sA[128 * 32];
  __shared__ short sB[128 * 32];
  const int tid = threadIdx.x;
  const int w = tid >> 6, lane = tid & 63;
  const int wm = w >> 1, wn = w & 1;
  const int g = lane >> 4, r16 = lane & 15;
  const int m0 = blockIdx.x * 128, n0 = blockIdx.y * 128;
  const int lrow = lane >> 2, slot = lane & 3;

  f32x4 acc[4][4] = {};

  for (int k0 = 0; k0 < 1024; k0 += 32) {
    __syncthreads();
    #pragma unroll
    for (int h = 0; h < 2; ++h) {
      int rbase = h * 64 + w * 16;
      int row = rbase + lrow;
      int sw = (row >> 1) & 3;
      GLD16(&A[(size_t)(m0 + row) * 1024 + k0 + ((slot ^ sw) * 8)], &sA[rbase * 32]);
      GLD16(&Bt[(size_t)(n0 + row) * 1024 + k0 + ((slot ^ sw) * 8)], &sB[rbase * 32]);
    }
    __syncthreads();
    bf16x8 af[4], bf[4];
    #pragma unroll
    for (int mi = 0; mi < 4; ++mi) {
      int row = wm * 64 + mi * 16 + r16;
      af[mi] = *(const bf16x8*)&sA[row * 32 + ((g ^ ((row >> 1) & 3)) * 8)];
    }
    #pragma unroll
    for (int ni = 0; ni < 4; ++ni) {
      int row = wn * 64 + ni * 16 + r16;
      bf[ni] = *(const bf16x8*)&sB[row * 32 + ((g ^ ((row >> 1) & 3)) * 8)];
    }
    #pragma unroll
    for (int mi = 0; mi < 4; ++mi)
      #pragma unroll
      for (int ni = 0; ni < 4; ++ni)
        acc[mi][ni] = __builtin_amdgcn_mfma_f32_16x16x32_bf16(af[mi], bf[ni], acc[mi][ni], 0, 0, 0);
  }

  #pragma unroll
  for (int mi = 0; mi < 4; ++mi) {
    #pragma unroll
    for (int ni = 0; ni < 4; ++ni) {
      int n = n0 + wn * 64 + ni * 16 + r16;
      float bv = bias[n];
      #pragma unroll
      for (int rr = 0; rr < 4; ++rr) {
        int m = m0 + wm * 64 + mi * 16 + g * 4 + rr;
        Out[(size_t)m * 1024 + n] = acc[mi][ni][rr] + bv;
      }
    }
  }
}

// ---------------- flash attention: 1 q-tile/block, LPT order, double-buffered K/V ----------------
// grid (bh=32, 32); qi = 31 - blockIdx.y so heavy (long-causal) blocks dispatch first.
// One __syncthreads per K-tile; tile kt+1 staged (K via global_load_lds, V via regs)
// while tile kt computes.
__global__ __launch_bounds__(256) void attn_fwd(const short* __restrict__ Q,
                                                const short* __restrict__ K,
                                                const short* __restrict__ V,
                                                short* __restrict__ O) {
  __shared__ short sK[2][64 * 64];   // [key][d], slot c holds d-chunk c^(key&7)
  __shared__ short vT[2][64 * 64];   // [d][key], slot c holds k-chunk c^(d&7)
  __shared__ short pl[4 * 16 * 64];  // per-wave P [row][key], slot c holds k-chunk c^(row&7)

  const int tid = threadIdx.x;
  const int w = tid >> 6, lane = tid & 63;
  const int g = lane >> 4, r16 = lane & 15;
  const int bh = blockIdx.x;
  const int b = bh >> 4, hh = bh & 15;
  const int qi = 31 - (int)blockIdx.y;  // LPT: heavy first
  const int q0 = qi * 64;

  const short* Qh = Q + (size_t)bh * T_ * D_;
  const short* Kh = K + (size_t)bh * T_ * D_;
  const short* Vh = V + (size_t)bh * T_ * D_;
  short* pw = &pl[w * 16 * 64];

  const int krow_in_wave = lane >> 3;
  const int kslot = lane & 7;
  const int kp = tid & 31;          // V staging: key pair index
  const int vd0 = (tid >> 5) * 8;   // V staging: d-chunk base
  const int vch = kp >> 2;          // k-chunk of keys 2kp,2kp+1
  const int ve = (kp & 3) * 2;      // element offset within chunk

  // Q fragments (A-frag): row = lane%16, k = c*32 + 8*(lane>>4) + j
  const int qrow_a = q0 + w * 16 + r16;
  bf16x8 qf[2];
  qf[0] = *(const bf16x8*)&Qh[(size_t)qrow_a * 64 + g * 8];
  qf[1] = *(const bf16x8*)&Qh[(size_t)qrow_a * 64 + 32 + g * 8];

  f32x4 o[4] = {};
  float mrow[4], lsum[4];
  #pragma unroll
  for (int r = 0; r < 4; ++r) { mrow[r] = -1e30f; lsum[r] = 0.f; }

  // ---- prologue: stage tile 0 into buffer 0 ----
  #pragma unroll
  for (int p = 0; p < 2; ++p) {
    int row = w * 16 + p * 8 + krow_in_wave;
    GLD16(&Kh[(size_t)row * 64 + ((kslot ^ (row & 7)) * 8)], &sK[0][(w * 16 + p * 8) * 64]);
  }
  {
    int4 v0 = *(const int4*)&Vh[(size_t)(2 * kp) * 64 + vd0];
    int4 v1 = *(const int4*)&Vh[(size_t)(2 * kp + 1) * 64 + vd0];
    const short* a0 = (const short*)&v0;
    const short* a1 = (const short*)&v1;
    #pragma unroll
    for (int j = 0; j < 8; ++j) {
      int d = vd0 + j;  // d&7 == j
      int val = ((int)(unsigned short)a0[j]) | (((int)(unsigned short)a1[j]) << 16);
      *(int*)&vT[0][d * 64 + ((vch ^ j) * 8) + ve] = val;
    }
  }
  __syncthreads();

  for (int kt = 0; kt <= qi; ++kt) {
    const int cur = kt & 1, nxt = cur ^ 1;
    const int k0 = kt * 64;
    const bool pf = (kt < qi);

    // ---- issue next-tile staging early (overlaps with compute below) ----
    int4 vn0, vn1;
    if (pf) {
      const int k1 = k0 + 64;
      #pragma unroll
      for (int p = 0; p < 2; ++p) {
        int row = w * 16 + p * 8 + krow_in_wave;
        GLD16(&Kh[(size_t)(k1 + row) * 64 + ((kslot ^ (row & 7)) * 8)],
              &sK[nxt][(w * 16 + p * 8) * 64]);
      }
      vn0 = *(const int4*)&Vh[(size_t)(k1 + 2 * kp) * 64 + vd0];
      vn1 = *(const int4*)&Vh[(size_t)(k1 + 2 * kp + 1) * 64 + vd0];
    }

    // ---- S = Q K^T from sK[cur] ----
    f32x4 s[4] = {};
    #pragma unroll
    for (int nt = 0; nt < 4; ++nt) {
      int row = nt * 16 + r16;
      #pragma unroll
      for (int c = 0; c < 2; ++c) {
        bf16x8 kf = *(const bf16x8*)&sK[cur][row * 64 + (((c * 4 + g) ^ (row & 7)) * 8)];
        s[nt] = __builtin_amdgcn_mfma_f32_16x16x32_bf16(qf[c], kf, s[nt], 0, 0, 0);
      }
    }

    // ---- online softmax ----
    const bool diag = (kt == qi);
    #pragma unroll
    for (int r = 0; r < 4; ++r) {
      int qrow = q0 + w * 16 + g * 4 + r;
      float v[4];
      #pragma unroll
      for (int nt = 0; nt < 4; ++nt) {
        v[nt] = s[nt][r] * 0.125f;
        if (diag && (k0 + nt * 16 + r16 > qrow)) v[nt] = -1e30f;
      }
      float mx = fmaxf(fmaxf(v[0], v[1]), fmaxf(v[2], v[3]));
      mx = fmaxf(mx, __shfl_xor(mx, 1));
      mx = fmaxf(mx, __shfl_xor(mx, 2));
      mx = fmaxf(mx, __shfl_xor(mx, 4));
      mx = fmaxf(mx, __shfl_xor(mx, 8));
      float mn = fmaxf(mrow[r], mx);
      float alpha = __expf(mrow[r] - mn);
      mrow[r] = mn;
      float p0 = __expf(v[0] - mn), p1 = __expf(v[1] - mn),
            p2 = __expf(v[2] - mn), p3 = __expf(v[3] - mn);
      float rs = (p0 + p1) + (p2 + p3);
      rs += __shfl_xor(rs, 1);
      rs += __shfl_xor(rs, 2);
      rs += __shfl_xor(rs, 4);
      rs += __shfl_xor(rs, 8);
      lsum[r] = lsum[r] * alpha + rs;
      o[0][r] *= alpha; o[1][r] *= alpha; o[2][r] *= alpha; o[3][r] *= alpha;

      int rw = g * 4 + r;
      int sw = rw & 7;
      int e = r16 & 7;
      pw[rw * 64 + ((kchunk_of(0, r16) ^ sw) * 8) + e] = f2bf(p0);
      pw[rw * 64 + ((kchunk_of(1, r16) ^ sw) * 8) + e] = f2bf(p1);
      pw[rw * 64 + ((kchunk_of(2, r16) ^ sw) * 8) + e] = f2bf(p2);
      pw[rw * 64 + ((kchunk_of(3, r16) ^ sw) * 8) + e] = f2bf(p3);
    }

    // ---- re-fragment P; O += P @ V from vT[cur] ----
    bf16x8 pa0 = *(const bf16x8*)&pw[r16 * 64 + ((g ^ (r16 & 7)) * 8)];
    bf16x8 pa1 = *(const bf16x8*)&pw[r16 * 64 + (((4 + g) ^ (r16 & 7)) * 8)];
    #pragma unroll
    for (int nt = 0; nt < 4; ++nt) {
      int d = nt * 16 + r16;
      bf16x8 vb0 = *(const bf16x8*)&vT[cur][d * 64 + ((g ^ (d & 7)) * 8)];
      bf16x8 vb1 = *(const bf16x8*)&vT[cur][d * 64 + (((4 + g) ^ (d & 7)) * 8)];
      o[nt] = __builtin_amdgcn_mfma_f32_16x16x32_bf16(pa0, vb0, o[nt], 0, 0, 0);
      o[nt] = __builtin_amdgcn_mfma_f32_16x16x32_bf16(pa1, vb1, o[nt], 0, 0, 0);
    }

    // ---- late half of async stage: write V^T[nxt] from regs ----
    if (pf) {
      const short* a0 = (const short*)&vn0;
      const short* a1 = (const short*)&vn1;
      #pragma unroll
      for (int j = 0; j < 8; ++j) {
        int d = vd0 + j;
        int val = ((int)(unsigned short)a0[j]) | (((int)(unsigned short)a1[j]) << 16);
        *(int*)&vT[nxt][d * 64 + ((vch ^ j) * 8) + ve] = val;
      }
    }
    __syncthreads();  // drains GLD16 (vmcnt) + ds_writes; all buffers ready
  }

  // ---- epilogue ----
  #pragma unroll
  for (int nt = 0; nt < 4; ++nt) {
    int d = nt * 16 + r16;
    #pragma unroll
    for (int r = 0; r < 4; ++r) {
      int t = q0 + w * 16 + g * 4 + r;
      O[(size_t)(b * T_ + t) * C_ + hh * 64 + d] = f2bf(o[nt][r] / lsum[r]);
    }
  }
}

extern "C" void kernel_launch(void* const* d_in, const int* in_sizes, int n_in,
                              void* d_out, int out_size, void* d_ws, size_t ws_size,
                              hipStream_t stream) {
  const float* x     = (const float*)d_in[0];
  const float* w_qkv = (const float*)d_in[1];
  const float* b_qkv = (const float*)d_in[2];
  const float* w_out = (const float*)d_in[3];
  const float* b_out = (const float*)d_in[4];
  float* out = (float*)d_out;

  char* ws = (char*)d_ws;
  if (ws_size < (size_t)(40u << 20)) return;

  short* xb     = (short*)(ws);                        // 8 MiB  [4096][1024] bf16
  short* wqkvT  = (short*)(ws + ((size_t)8u << 20));   // 6 MiB  [3072][1024] bf16
  short* woutT  = (short*)(ws + ((size_t)14u << 20));  // 2 MiB  [1024][1024] bf16
  short* Qb     = (short*)(ws + ((size_t)16u << 20));  // 8 MiB  [B][H][T][D]
  short* Kb     = (short*)(ws + ((size_t)24u << 20));  // 8 MiB
  short* Vb     = (short*)(ws + ((size_t)32u << 20));  // 8 MiB
  short* attn_o = xb;  // xb dead after gemm_qkv

  cast_f32_bf16<<<4096, 256, 0, stream>>>(x, xb);
  transpose_cast<<<dim3(96, 32), dim3(32, 8), 0, stream>>>(w_qkv, wqkvT, 1024, 3072);
  transpose_cast<<<dim3(32, 32), dim3(32, 8), 0, stream>>>(w_out, woutT, 1024, 1024);
  gemm_qkv<<<dim3(32, 24), 256, 0, stream>>>(xb, wqkvT, b_qkv, Qb, Kb, Vb);
  attn_fwd<<<dim3(32, 32), 256, 0, stream>>>(Qb, Kb, Vb, attn_o);
  gemm_out<<<dim3(32, 8), 256, 0, stream>>>(attn_o, woutT, b_out, out);
}

// Round 4
// 145.646 us; speedup vs baseline: 1.8711x; 1.0515x over previous
//
#include <hip/hip_runtime.h>

#define B_ 2
#define T_ 2048
#define C_ 1024
#define H_ 16
#define D_ 64

using bf16x8 = __attribute__((ext_vector_type(8))) short;
using f32x4  = __attribute__((ext_vector_type(4))) float;

static __device__ __forceinline__ short f2bf(float f) {
  unsigned u = __builtin_bit_cast(unsigned, f);
  unsigned r = u + 0x7fffu + ((u >> 16) & 1u);
  return (short)(r >> 16);
}

#define GLD16(gp, lp) __builtin_amdgcn_global_load_lds( \
    (const __attribute__((address_space(1))) void*)(gp), \
    (__attribute__((address_space(3))) void*)(lp), 16, 0, 0)

// ---------------- cast f32 -> bf16 (vectorized) ----------------
__global__ __launch_bounds__(256) void cast_f32_bf16(const float* __restrict__ in,
                                                     short* __restrict__ out) {
  int i = blockIdx.x * blockDim.x + threadIdx.x;
  float4 v = ((const float4*)in)[i];
  short4 o;
  o.x = f2bf(v.x); o.y = f2bf(v.y); o.z = f2bf(v.z); o.w = f2bf(v.w);
  ((short4*)out)[i] = o;
}

// ---------------- transpose + cast: in [R][N] f32 -> out [N][R] bf16 ----------------
__global__ __launch_bounds__(256) void transpose_cast(const float* __restrict__ in,
                                                      short* __restrict__ out,
                                                      int R, int N) {
  __shared__ float tile[32][33];
  int bx = blockIdx.x * 32, by = blockIdx.y * 32;
  int tx = threadIdx.x, ty = threadIdx.y;
  #pragma unroll
  for (int j = 0; j < 32; j += 8)
    tile[ty + j][tx] = in[(size_t)(by + ty + j) * N + bx + tx];
  __syncthreads();
  #pragma unroll
  for (int j = 0; j < 32; j += 8)
    out[(size_t)(bx + ty + j) * R + by + tx] = f2bf(tile[tx][ty + j]);
}

// ---------------- GEMM: 128x128 tile, BK=32, 4 waves, global_load_lds staging ----------------
// Q output is prescaled by 0.125*log2(e) so attention can use exp2 directly.
__global__ __launch_bounds__(256) void gemm_qkv(const short* __restrict__ A,
                                                const short* __restrict__ Bt,
                                                const float* __restrict__ bias,
                                                short* __restrict__ Qo,
                                                short* __restrict__ Ko,
                                                short* __restrict__ Vo) {
  __shared__ short sA[128 * 32];
  __shared__ short sB[128 * 32];
  const int tid = threadIdx.x;
  const int w = tid >> 6, lane = tid & 63;
  const int wm = w >> 1, wn = w & 1;
  const int g = lane >> 4, r16 = lane & 15;
  const int m0 = blockIdx.x * 128, n0 = blockIdx.y * 128;
  const int lrow = lane >> 2, slot = lane & 3;

  f32x4 acc[4][4] = {};

  for (int k0 = 0; k0 < 1024; k0 += 32) {
    __syncthreads();
    #pragma unroll
    for (int h = 0; h < 2; ++h) {
      int rbase = h * 64 + w * 16;
      int row = rbase + lrow;
      int sw = (row >> 1) & 3;
      GLD16(&A[(size_t)(m0 + row) * 1024 + k0 + ((slot ^ sw) * 8)], &sA[rbase * 32]);
      GLD16(&Bt[(size_t)(n0 + row) * 1024 + k0 + ((slot ^ sw) * 8)], &sB[rbase * 32]);
    }
    __syncthreads();
    bf16x8 af[4], bf[4];
    #pragma unroll
    for (int mi = 0; mi < 4; ++mi) {
      int row = wm * 64 + mi * 16 + r16;
      af[mi] = *(const bf16x8*)&sA[row * 32 + ((g ^ ((row >> 1) & 3)) * 8)];
    }
    #pragma unroll
    for (int ni = 0; ni < 4; ++ni) {
      int row = wn * 64 + ni * 16 + r16;
      bf[ni] = *(const bf16x8*)&sB[row * 32 + ((g ^ ((row >> 1) & 3)) * 8)];
    }
    #pragma unroll
    for (int mi = 0; mi < 4; ++mi)
      #pragma unroll
      for (int ni = 0; ni < 4; ++ni)
        acc[mi][ni] = __builtin_amdgcn_mfma_f32_16x16x32_bf16(af[mi], bf[ni], acc[mi][ni], 0, 0, 0);
  }

  #pragma unroll
  for (int mi = 0; mi < 4; ++mi) {
    #pragma unroll
    for (int ni = 0; ni < 4; ++ni) {
      int n = n0 + wn * 64 + ni * 16 + r16;
      float bv = bias[n];
      int which = n >> 10;
      int c = n & 1023;
      int hh = c >> 6, d = c & 63;
      short* dst = (which == 0) ? Qo : ((which == 1) ? Ko : Vo);
      float sc = (which == 0) ? 0.18033688f : 1.0f;  // 0.125 * log2(e) folded into Q
      #pragma unroll
      for (int rr = 0; rr < 4; ++rr) {
        int m = m0 + wm * 64 + mi * 16 + g * 4 + rr;
        int b = m >> 11, t = m & 2047;
        dst[(size_t)((b * H_ + hh) * T_ + t) * D_ + d] = f2bf((acc[mi][ni][rr] + bv) * sc);
      }
    }
  }
}

__global__ __launch_bounds__(256) void gemm_out(const short* __restrict__ A,
                                                const short* __restrict__ Bt,
                                                const float* __restrict__ bias,
                                                float* __restrict__ Out) {
  __shared__ short sA[128 * 32];
  __shared__ short sB[128 * 32];
  const int tid = threadIdx.x;
  const int w = tid >> 6, lane = tid & 63;
  const int wm = w >> 1, wn = w & 1;
  const int g = lane >> 4, r16 = lane & 15;
  const int m0 = blockIdx.x * 128, n0 = blockIdx.y * 128;
  const int lrow = lane >> 2, slot = lane & 3;

  f32x4 acc[4][4] = {};

  for (int k0 = 0; k0 < 1024; k0 += 32) {
    __syncthreads();
    #pragma unroll
    for (int h = 0; h < 2; ++h) {
      int rbase = h * 64 + w * 16;
      int row = rbase + lrow;
      int sw = (row >> 1) & 3;
      GLD16(&A[(size_t)(m0 + row) * 1024 + k0 + ((slot ^ sw) * 8)], &sA[rbase * 32]);
      GLD16(&Bt[(size_t)(n0 + row) * 1024 + k0 + ((slot ^ sw) * 8)], &sB[rbase * 32]);
    }
    __syncthreads();
    bf16x8 af[4], bf[4];
    #pragma unroll
    for (int mi = 0; mi < 4; ++mi) {
      int row = wm * 64 + mi * 16 + r16;
      af[mi] = *(const bf16x8*)&sA[row * 32 + ((g ^ ((row >> 1) & 3)) * 8)];
    }
    #pragma unroll
    for (int ni = 0; ni < 4; ++ni) {
      int row = wn * 64 + ni * 16 + r16;
      bf[ni] = *(const bf16x8*)&sB[row * 32 + ((g ^ ((row >> 1) & 3)) * 8)];
    }
    #pragma unroll
    for (int mi = 0; mi < 4; ++mi)
      #pragma unroll
      for (int ni = 0; ni < 4; ++ni)
        acc[mi][ni] = __builtin_amdgcn_mfma_f32_16x16x32_bf16(af[mi], bf[ni], acc[mi][ni], 0, 0, 0);
  }

  #pragma unroll
  for (int mi = 0; mi < 4; ++mi) {
    #pragma unroll
    for (int ni = 0; ni < 4; ++ni) {
      int n = n0 + wn * 64 + ni * 16 + r16;
      float bv = bias[n];
      #pragma unroll
      for (int rr = 0; rr < 4; ++rr) {
        int m = m0 + wm * 64 + mi * 16 + g * 4 + rr;
        Out[(size_t)m * 1024 + n] = acc[mi][ni][rr] + bv;
      }
    }
  }
}

// ---------------- flash attention: swapped QK^T, in-register softmax/P ----------------
// grid (bh=32, 16); q-tile = 128 rows (4 waves x 32 q each), KVBLK = 64, double-buffered.
// mfma(K,Q) puts a full 64-key S-row per lane-quad -> softmax needs only 2 shfl_xor.
// P packed via v_cvt_pk_bf16_f32 stays in registers; V^T stored slot-permuted so the
// packed P IS the PV A-fragment (zero shuffles, zero P-LDS).
__global__ __launch_bounds__(256) void attn_fwd(const short* __restrict__ Q,
                                                const short* __restrict__ K,
                                                const short* __restrict__ V,
                                                short* __restrict__ O) {
  __shared__ short sK[2][64 * 64];   // [key][d], chunk c holds d-chunk c^(key&7)
  __shared__ short vT[2][64 * 64];   // [d][slot], slot = pi(key); chunk c' holds c'^(d&7)

  const int tid = threadIdx.x;
  const int w = tid >> 6, lane = tid & 63;
  const int g = lane >> 4, r16 = lane & 15;
  const int bh = blockIdx.x;
  const int b = bh >> 4, hh = bh & 15;
  const int qi = 15 - (int)blockIdx.y;  // LPT: heavy first
  const int q0 = qi * 128;

  const short* Qh = Q + (size_t)bh * T_ * D_;
  const short* Kh = K + (size_t)bh * T_ * D_;
  const short* Vh = V + (size_t)bh * T_ * D_;

  // K staging (as R2, verified conflict-free)
  const int krow_in_wave = lane >> 3;
  const int kslot = lane & 7;
  // V staging: thread loads keys 2kp,2kp+1 for d-chunk vd0; store slot-permuted:
  // key = 32c + 16nt2 + 4gk + r  ->  slot = 32c + 8gk + 4nt2 + r
  const int kp = tid & 31;
  const int vd0 = (tid >> 5) * 8;
  const int vchunk = (kp >> 4) * 4 + ((kp & 7) >> 1);  // slot>>3
  const int velem  = ((kp >> 3) & 1) * 4 + 2 * (kp & 1);

  // Q fragments: 2 q-subtiles of 16 rows each (q = q0 + w*32 + u*16 + r16)
  bf16x8 qf[2][2];
  #pragma unroll
  for (int u = 0; u < 2; ++u) {
    int qrow = q0 + w * 32 + u * 16 + r16;
    qf[u][0] = *(const bf16x8*)&Qh[(size_t)qrow * 64 + g * 8];
    qf[u][1] = *(const bf16x8*)&Qh[(size_t)qrow * 64 + 32 + g * 8];
  }

  f32x4 o[2][4] = {};
  float m_[2] = {-1e30f, -1e30f}, l_[2] = {0.f, 0.f};

  const int nkt = 2 * qi + 2;  // 64-key tiles covering q0..q0+127

  // ---- prologue: stage tile 0 ----
  #pragma unroll
  for (int p = 0; p < 2; ++p) {
    int row = w * 16 + p * 8 + krow_in_wave;
    GLD16(&Kh[(size_t)row * 64 + ((kslot ^ (row & 7)) * 8)], &sK[0][(w * 16 + p * 8) * 64]);
  }
  {
    int4 v0 = *(const int4*)&Vh[(size_t)(2 * kp) * 64 + vd0];
    int4 v1 = *(const int4*)&Vh[(size_t)(2 * kp + 1) * 64 + vd0];
    const short* a0 = (const short*)&v0;
    const short* a1 = (const short*)&v1;
    #pragma unroll
    for (int j = 0; j < 8; ++j) {
      int d = vd0 + j;  // d&7 == j
      int val = ((int)(unsigned short)a0[j]) | (((int)(unsigned short)a1[j]) << 16);
      *(int*)&vT[0][d * 64 + ((vchunk ^ j) * 8) + velem] = val;
    }
  }
  __syncthreads();

  for (int kt = 0; kt < nkt; ++kt) {
    const int cur = kt & 1, nxt = cur ^ 1;
    const int k0 = kt * 64;
    const bool pf = (kt + 1 < nkt);

    // ---- issue next-tile staging early ----
    int4 vn0, vn1;
    if (pf) {
      const int k1 = k0 + 64;
      #pragma unroll
      for (int p = 0; p < 2; ++p) {
        int row = w * 16 + p * 8 + krow_in_wave;
        GLD16(&Kh[(size_t)(k1 + row) * 64 + ((kslot ^ (row & 7)) * 8)],
              &sK[nxt][(w * 16 + p * 8) * 64]);
      }
      vn0 = *(const int4*)&Vh[(size_t)(k1 + 2 * kp) * 64 + vd0];
      vn1 = *(const int4*)&Vh[(size_t)(k1 + 2 * kp + 1) * 64 + vd0];
    }

    // ---- S^T = K Q^T : lane holds S[key = nt*16+4g+rr][q = r16] ----
    f32x4 s[2][4] = {};
    #pragma unroll
    for (int nt = 0; nt < 4; ++nt) {
      const int row = nt * 16 + r16;
      const int sw8 = r16 & 7;
      bf16x8 kf0 = *(const bf16x8*)&sK[cur][row * 64 + ((g ^ sw8) * 8)];
      bf16x8 kf1 = *(const bf16x8*)&sK[cur][row * 64 + (((4 + g) ^ sw8) * 8)];
      s[0][nt] = __builtin_amdgcn_mfma_f32_16x16x32_bf16(kf0, qf[0][0], s[0][nt], 0, 0, 0);
      s[0][nt] = __builtin_amdgcn_mfma_f32_16x16x32_bf16(kf1, qf[0][1], s[0][nt], 0, 0, 0);
      s[1][nt] = __builtin_amdgcn_mfma_f32_16x16x32_bf16(kf0, qf[1][0], s[1][nt], 0, 0, 0);
      s[1][nt] = __builtin_amdgcn_mfma_f32_16x16x32_bf16(kf1, qf[1][1], s[1][nt], 0, 0, 0);
    }

    // ---- online softmax (log2 domain; Q prescaled) ----
    const bool tail = (kt >= nkt - 2);
    int pk[2][8];
    #pragma unroll
    for (int u = 0; u < 2; ++u) {
      if (tail) {
        const int qrow = q0 + w * 32 + u * 16 + r16;
        #pragma unroll
        for (int nt = 0; nt < 4; ++nt)
          #pragma unroll
          for (int rr = 0; rr < 4; ++rr)
            if (k0 + nt * 16 + 4 * g + rr > qrow) s[u][nt][rr] = -1e30f;
      }
      float pmax = s[u][0][0];
      #pragma unroll
      for (int nt = 0; nt < 4; ++nt)
        #pragma unroll
        for (int rr = 0; rr < 4; ++rr)
          pmax = fmaxf(pmax, s[u][nt][rr]);
      pmax = fmaxf(pmax, __shfl_xor(pmax, 16));
      pmax = fmaxf(pmax, __shfl_xor(pmax, 32));
      if (!__all(pmax - m_[u] <= 8.0f)) {  // defer-max (T13), log2 domain
        float mn = fmaxf(m_[u], pmax);
        float al = __builtin_amdgcn_exp2f(m_[u] - mn);
        m_[u] = mn;
        l_[u] *= al;
        float av[4];
        #pragma unroll
        for (int rr = 0; rr < 4; ++rr) av[rr] = __shfl(al, 4 * g + rr, 16);
        #pragma unroll
        for (int nt = 0; nt < 4; ++nt)
          #pragma unroll
          for (int rr = 0; rr < 4; ++rr) o[u][nt][rr] *= av[rr];
      }
      float rs = 0.f;
      #pragma unroll
      for (int nt = 0; nt < 4; ++nt)
        #pragma unroll
        for (int rr = 0; rr < 4; ++rr) {
          float p = __builtin_amdgcn_exp2f(s[u][nt][rr] - m_[u]);
          s[u][nt][rr] = p;
          rs += p;
        }
      rs += __shfl_xor(rs, 16);
      rs += __shfl_xor(rs, 32);
      l_[u] += rs;
      #pragma unroll
      for (int nt = 0; nt < 4; ++nt)
        #pragma unroll
        for (int h = 0; h < 2; ++h)
          asm("v_cvt_pk_bf16_f32 %0, %1, %2"
              : "=v"(pk[u][nt * 2 + h])
              : "v"(s[u][nt][2 * h]), "v"(s[u][nt][2 * h + 1]));
    }

    // ---- O += P @ V : packed P is the A-fragment directly ----
    bf16x8 pa[2][2];
    #pragma unroll
    for (int u = 0; u < 2; ++u) {
      int4 t0; t0.x = pk[u][0]; t0.y = pk[u][1]; t0.z = pk[u][2]; t0.w = pk[u][3];
      int4 t1; t1.x = pk[u][4]; t1.y = pk[u][5]; t1.z = pk[u][6]; t1.w = pk[u][7];
      pa[u][0] = __builtin_bit_cast(bf16x8, t0);
      pa[u][1] = __builtin_bit_cast(bf16x8, t1);
    }
    #pragma unroll
    for (int nt = 0; nt < 4; ++nt) {
      const int d = nt * 16 + r16;
      bf16x8 vb0 = *(const bf16x8*)&vT[cur][d * 64 + ((g ^ (d & 7)) * 8)];
      bf16x8 vb1 = *(const bf16x8*)&vT[cur][d * 64 + (((4 + g) ^ (d & 7)) * 8)];
      o[0][nt] = __builtin_amdgcn_mfma_f32_16x16x32_bf16(pa[0][0], vb0, o[0][nt], 0, 0, 0);
      o[0][nt] = __builtin_amdgcn_mfma_f32_16x16x32_bf16(pa[0][1], vb1, o[0][nt], 0, 0, 0);
      o[1][nt] = __builtin_amdgcn_mfma_f32_16x16x32_bf16(pa[1][0], vb0, o[1][nt], 0, 0, 0);
      o[1][nt] = __builtin_amdgcn_mfma_f32_16x16x32_bf16(pa[1][1], vb1, o[1][nt], 0, 0, 0);
    }

    // ---- late half of async stage: write V^T[nxt] from regs ----
    if (pf) {
      const short* a0 = (const short*)&vn0;
      const short* a1 = (const short*)&vn1;
      #pragma unroll
      for (int j = 0; j < 8; ++j) {
        int d = vd0 + j;
        int val = ((int)(unsigned short)a0[j]) | (((int)(unsigned short)a1[j]) << 16);
        *(int*)&vT[nxt][d * 64 + ((vchunk ^ j) * 8) + velem] = val;
      }
    }
    __syncthreads();
  }

  // ---- epilogue: O /= l (l broadcast from softmax lanes) ----
  #pragma unroll
  for (int u = 0; u < 2; ++u) {
    float lv[4];
    #pragma unroll
    for (int rr = 0; rr < 4; ++rr) lv[rr] = __shfl(l_[u], 4 * g + rr, 16);
    #pragma unroll
    for (int nt = 0; nt < 4; ++nt) {
      int d = nt * 16 + r16;
      #pragma unroll
      for (int rr = 0; rr < 4; ++rr) {
        int t = q0 + w * 32 + u * 16 + 4 * g + rr;
        O[(size_t)(b * T_ + t) * C_ + hh * 64 + d] = f2bf(o[u][nt][rr] / lv[rr]);
      }
    }
  }
}

extern "C" void kernel_launch(void* const* d_in, const int* in_sizes, int n_in,
                              void* d_out, int out_size, void* d_ws, size_t ws_size,
                              hipStream_t stream) {
  const float* x     = (const float*)d_in[0];
  const float* w_qkv = (const float*)d_in[1];
  const float* b_qkv = (const float*)d_in[2];
  const float* w_out = (const float*)d_in[3];
  const float* b_out = (const float*)d_in[4];
  float* out = (float*)d_out;

  char* ws = (char*)d_ws;
  if (ws_size < (size_t)(40u << 20)) return;

  short* xb     = (short*)(ws);                        // 8 MiB  [4096][1024] bf16
  short* wqkvT  = (short*)(ws + ((size_t)8u << 20));   // 6 MiB  [3072][1024] bf16
  short* woutT  = (short*)(ws + ((size_t)14u << 20));  // 2 MiB  [1024][1024] bf16
  short* Qb     = (short*)(ws + ((size_t)16u << 20));  // 8 MiB  [B][H][T][D] (prescaled)
  short* Kb     = (short*)(ws + ((size_t)24u << 20));  // 8 MiB
  short* Vb     = (short*)(ws + ((size_t)32u << 20));  // 8 MiB
  short* attn_o = xb;  // xb dead after gemm_qkv

  cast_f32_bf16<<<4096, 256, 0, stream>>>(x, xb);
  transpose_cast<<<dim3(96, 32), dim3(32, 8), 0, stream>>>(w_qkv, wqkvT, 1024, 3072);
  transpose_cast<<<dim3(32, 32), dim3(32, 8), 0, stream>>>(w_out, woutT, 1024, 1024);
  gemm_qkv<<<dim3(32, 24), 256, 0, stream>>>(xb, wqkvT, b_qkv, Qb, Kb, Vb);
  attn_fwd<<<dim3(32, 16), 256, 0, stream>>>(Qb, Kb, Vb, attn_o);
  gemm_out<<<dim3(32, 8), 256, 0, stream>>>(attn_o, woutT, b_out, out);
}

// Round 5
// 134.252 us; speedup vs baseline: 2.0299x; 1.0849x over previous
//
#include <hip/hip_runtime.h>

#define B_ 2
#define T_ 2048
#define C_ 1024
#define H_ 16
#define D_ 64

using bf16x8 = __attribute__((ext_vector_type(8))) short;
using f32x4  = __attribute__((ext_vector_type(4))) float;

static __device__ __forceinline__ short f2bf(float f) {
  unsigned u = __builtin_bit_cast(unsigned, f);
  unsigned r = u + 0x7fffu + ((u >> 16) & 1u);
  return (short)(r >> 16);
}

#define GLD16(gp, lp) __builtin_amdgcn_global_load_lds( \
    (const __attribute__((address_space(1))) void*)(gp), \
    (__attribute__((address_space(3))) void*)(lp), 16, 0, 0)

// ---------------- cast f32 -> bf16 (vectorized) ----------------
__global__ __launch_bounds__(256) void cast_f32_bf16(const float* __restrict__ in,
                                                     short* __restrict__ out) {
  int i = blockIdx.x * blockDim.x + threadIdx.x;
  float4 v = ((const float4*)in)[i];
  short4 o;
  o.x = f2bf(v.x); o.y = f2bf(v.y); o.z = f2bf(v.z); o.w = f2bf(v.w);
  ((short4*)out)[i] = o;
}

// ---------------- transpose + cast: in [R][N] f32 -> out [N][R] bf16 ----------------
__global__ __launch_bounds__(256) void transpose_cast(const float* __restrict__ in,
                                                      short* __restrict__ out,
                                                      int R, int N) {
  __shared__ float tile[32][33];
  int bx = blockIdx.x * 32, by = blockIdx.y * 32;
  int tx = threadIdx.x, ty = threadIdx.y;
  #pragma unroll
  for (int j = 0; j < 32; j += 8)
    tile[ty + j][tx] = in[(size_t)(by + ty + j) * N + bx + tx];
  __syncthreads();
  #pragma unroll
  for (int j = 0; j < 32; j += 8)
    out[(size_t)(bx + ty + j) * R + by + tx] = f2bf(tile[tx][ty + j]);
}

// ---------------- GEMM: 128x128 tile, BK=32, 4 waves, global_load_lds staging ----------------
// Q output is prescaled by 0.125*log2(e) so attention can use exp2 directly.
__global__ __launch_bounds__(256) void gemm_qkv(const short* __restrict__ A,
                                                const short* __restrict__ Bt,
                                                const float* __restrict__ bias,
                                                short* __restrict__ Qo,
                                                short* __restrict__ Ko,
                                                short* __restrict__ Vo) {
  __shared__ short sA[128 * 32];
  __shared__ short sB[128 * 32];
  const int tid = threadIdx.x;
  const int w = tid >> 6, lane = tid & 63;
  const int wm = w >> 1, wn = w & 1;
  const int g = lane >> 4, r16 = lane & 15;
  const int m0 = blockIdx.x * 128, n0 = blockIdx.y * 128;
  const int lrow = lane >> 2, slot = lane & 3;

  f32x4 acc[4][4] = {};

  for (int k0 = 0; k0 < 1024; k0 += 32) {
    __syncthreads();
    #pragma unroll
    for (int h = 0; h < 2; ++h) {
      int rbase = h * 64 + w * 16;
      int row = rbase + lrow;
      int sw = (row >> 1) & 3;
      GLD16(&A[(size_t)(m0 + row) * 1024 + k0 + ((slot ^ sw) * 8)], &sA[rbase * 32]);
      GLD16(&Bt[(size_t)(n0 + row) * 1024 + k0 + ((slot ^ sw) * 8)], &sB[rbase * 32]);
    }
    __syncthreads();
    bf16x8 af[4], bf[4];
    #pragma unroll
    for (int mi = 0; mi < 4; ++mi) {
      int row = wm * 64 + mi * 16 + r16;
      af[mi] = *(const bf16x8*)&sA[row * 32 + ((g ^ ((row >> 1) & 3)) * 8)];
    }
    #pragma unroll
    for (int ni = 0; ni < 4; ++ni) {
      int row = wn * 64 + ni * 16 + r16;
      bf[ni] = *(const bf16x8*)&sB[row * 32 + ((g ^ ((row >> 1) & 3)) * 8)];
    }
    __builtin_amdgcn_s_setprio(1);
    #pragma unroll
    for (int mi = 0; mi < 4; ++mi)
      #pragma unroll
      for (int ni = 0; ni < 4; ++ni)
        acc[mi][ni] = __builtin_amdgcn_mfma_f32_16x16x32_bf16(af[mi], bf[ni], acc[mi][ni], 0, 0, 0);
    __builtin_amdgcn_s_setprio(0);
  }

  #pragma unroll
  for (int mi = 0; mi < 4; ++mi) {
    #pragma unroll
    for (int ni = 0; ni < 4; ++ni) {
      int n = n0 + wn * 64 + ni * 16 + r16;
      float bv = bias[n];
      int which = n >> 10;
      int c = n & 1023;
      int hh = c >> 6, d = c & 63;
      short* dst = (which == 0) ? Qo : ((which == 1) ? Ko : Vo);
      float sc = (which == 0) ? 0.18033688f : 1.0f;  // 0.125 * log2(e) folded into Q
      #pragma unroll
      for (int rr = 0; rr < 4; ++rr) {
        int m = m0 + wm * 64 + mi * 16 + g * 4 + rr;
        int b = m >> 11, t = m & 2047;
        dst[(size_t)((b * H_ + hh) * T_ + t) * D_ + d] = f2bf((acc[mi][ni][rr] + bv) * sc);
      }
    }
  }
}

__global__ __launch_bounds__(256) void gemm_out(const short* __restrict__ A,
                                                const short* __restrict__ Bt,
                                                const float* __restrict__ bias,
                                                float* __restrict__ Out) {
  __shared__ short sA[128 * 32];
  __shared__ short sB[128 * 32];
  const int tid = threadIdx.x;
  const int w = tid >> 6, lane = tid & 63;
  const int wm = w >> 1, wn = w & 1;
  const int g = lane >> 4, r16 = lane & 15;
  const int m0 = blockIdx.x * 128, n0 = blockIdx.y * 128;
  const int lrow = lane >> 2, slot = lane & 3;

  f32x4 acc[4][4] = {};

  for (int k0 = 0; k0 < 1024; k0 += 32) {
    __syncthreads();
    #pragma unroll
    for (int h = 0; h < 2; ++h) {
      int rbase = h * 64 + w * 16;
      int row = rbase + lrow;
      int sw = (row >> 1) & 3;
      GLD16(&A[(size_t)(m0 + row) * 1024 + k0 + ((slot ^ sw) * 8)], &sA[rbase * 32]);
      GLD16(&Bt[(size_t)(n0 + row) * 1024 + k0 + ((slot ^ sw) * 8)], &sB[rbase * 32]);
    }
    __syncthreads();
    bf16x8 af[4], bf[4];
    #pragma unroll
    for (int mi = 0; mi < 4; ++mi) {
      int row = wm * 64 + mi * 16 + r16;
      af[mi] = *(const bf16x8*)&sA[row * 32 + ((g ^ ((row >> 1) & 3)) * 8)];
    }
    #pragma unroll
    for (int ni = 0; ni < 4; ++ni) {
      int row = wn * 64 + ni * 16 + r16;
      bf[ni] = *(const bf16x8*)&sB[row * 32 + ((g ^ ((row >> 1) & 3)) * 8)];
    }
    __builtin_amdgcn_s_setprio(1);
    #pragma unroll
    for (int mi = 0; mi < 4; ++mi)
      #pragma unroll
      for (int ni = 0; ni < 4; ++ni)
        acc[mi][ni] = __builtin_amdgcn_mfma_f32_16x16x32_bf16(af[mi], bf[ni], acc[mi][ni], 0, 0, 0);
    __builtin_amdgcn_s_setprio(0);
  }

  #pragma unroll
  for (int mi = 0; mi < 4; ++mi) {
    #pragma unroll
    for (int ni = 0; ni < 4; ++ni) {
      int n = n0 + wn * 64 + ni * 16 + r16;
      float bv = bias[n];
      #pragma unroll
      for (int rr = 0; rr < 4; ++rr) {
        int m = m0 + wm * 64 + mi * 16 + g * 4 + rr;
        Out[(size_t)m * 1024 + n] = acc[mi][ni][rr] + bv;
      }
    }
  }
}

// ---------------- flash attention: 64-row q-tiles, 4 blocks/CU, swapped QK^T ----------------
// grid (bh=32, 32); qi = 31 - blockIdx.y (LPT). Block = 4 waves x 16 q-rows.
// Swapped mfma(K,Q): lane holds 16 S-values for one q-row; softmax = in-reg reduce
// + 2 shfl_xor. P packed via v_cvt_pk_bf16_f32 feeds PV directly (V^T slot-permuted).
__global__ __launch_bounds__(256, 4) void attn_fwd(const short* __restrict__ Q,
                                                   const short* __restrict__ K,
                                                   const short* __restrict__ V,
                                                   short* __restrict__ O) {
  __shared__ short sK[2][64 * 64];   // [key][d], chunk c holds d-chunk c^(key&7)
  __shared__ short vT[2][64 * 64];   // [d][slot], slot = pi(key); chunk c' holds c'^(d&7)

  const int tid = threadIdx.x;
  const int w = tid >> 6, lane = tid & 63;
  const int g = lane >> 4, r16 = lane & 15;
  const int bh = blockIdx.x;
  const int b = bh >> 4, hh = bh & 15;
  const int qi = 31 - (int)blockIdx.y;  // LPT: heavy first
  const int q0 = qi * 64;

  const short* Qh = Q + (size_t)bh * T_ * D_;
  const short* Kh = K + (size_t)bh * T_ * D_;
  const short* Vh = V + (size_t)bh * T_ * D_;

  const int krow_in_wave = lane >> 3;
  const int kslot = lane & 7;
  // V slot permutation: slot = 32a + 8c + 4b + 2d + e for key = 32a+16b+4c+2d+e
  const int kp = tid & 31;
  const int vd0 = (tid >> 5) * 8;
  const int vchunk = (kp >> 4) * 4 + ((kp & 7) >> 1);
  const int velem  = ((kp >> 3) & 1) * 4 + 2 * (kp & 1);

  // Q fragment: wave's 16 q-rows, q = q0 + w*16 + r16
  const int qrow_a = q0 + w * 16 + r16;
  bf16x8 qf[2];
  qf[0] = *(const bf16x8*)&Qh[(size_t)qrow_a * 64 + g * 8];
  qf[1] = *(const bf16x8*)&Qh[(size_t)qrow_a * 64 + 32 + g * 8];

  f32x4 o[4] = {};
  float m_ = -1e30f, l_ = 0.f;

  const int nkt = qi + 1;

  // ---- prologue: stage tile 0 ----
  #pragma unroll
  for (int p = 0; p < 2; ++p) {
    int row = w * 16 + p * 8 + krow_in_wave;
    GLD16(&Kh[(size_t)row * 64 + ((kslot ^ (row & 7)) * 8)], &sK[0][(w * 16 + p * 8) * 64]);
  }
  {
    int4 v0 = *(const int4*)&Vh[(size_t)(2 * kp) * 64 + vd0];
    int4 v1 = *(const int4*)&Vh[(size_t)(2 * kp + 1) * 64 + vd0];
    const short* a0 = (const short*)&v0;
    const short* a1 = (const short*)&v1;
    #pragma unroll
    for (int j = 0; j < 8; ++j) {
      int d = vd0 + j;  // d&7 == j
      int val = ((int)(unsigned short)a0[j]) | (((int)(unsigned short)a1[j]) << 16);
      *(int*)&vT[0][d * 64 + ((vchunk ^ j) * 8) + velem] = val;
    }
  }
  __syncthreads();

  for (int kt = 0; kt < nkt; ++kt) {
    const int cur = kt & 1, nxt = cur ^ 1;
    const int k0 = kt * 64;
    const bool pf = (kt + 1 < nkt);

    // ---- issue next-tile staging early (T14) ----
    int4 vn0, vn1;
    if (pf) {
      const int k1 = k0 + 64;
      #pragma unroll
      for (int p = 0; p < 2; ++p) {
        int row = w * 16 + p * 8 + krow_in_wave;
        GLD16(&Kh[(size_t)(k1 + row) * 64 + ((kslot ^ (row & 7)) * 8)],
              &sK[nxt][(w * 16 + p * 8) * 64]);
      }
      vn0 = *(const int4*)&Vh[(size_t)(k1 + 2 * kp) * 64 + vd0];
      vn1 = *(const int4*)&Vh[(size_t)(k1 + 2 * kp + 1) * 64 + vd0];
    }

    // ---- S^T = K Q^T : lane holds S[key = nt*16+4g+rr][q = r16] ----
    f32x4 s[4] = {};
    __builtin_amdgcn_s_setprio(1);
    #pragma unroll
    for (int nt = 0; nt < 4; ++nt) {
      const int row = nt * 16 + r16;
      const int sw8 = r16 & 7;
      bf16x8 kf0 = *(const bf16x8*)&sK[cur][row * 64 + ((g ^ sw8) * 8)];
      bf16x8 kf1 = *(const bf16x8*)&sK[cur][row * 64 + (((4 + g) ^ sw8) * 8)];
      s[nt] = __builtin_amdgcn_mfma_f32_16x16x32_bf16(kf0, qf[0], s[nt], 0, 0, 0);
      s[nt] = __builtin_amdgcn_mfma_f32_16x16x32_bf16(kf1, qf[1], s[nt], 0, 0, 0);
    }
    __builtin_amdgcn_s_setprio(0);

    // ---- online softmax (log2 domain; Q prescaled) ----
    if (kt == nkt - 1) {  // diagonal tile only
      const int qrow = w * 16 + r16;  // relative to q0 == k0
      #pragma unroll
      for (int nt = 0; nt < 4; ++nt)
        #pragma unroll
        for (int rr = 0; rr < 4; ++rr)
          if (nt * 16 + 4 * g + rr > qrow) s[nt][rr] = -1e30f;
    }
    float pmax = s[0][0];
    #pragma unroll
    for (int nt = 0; nt < 4; ++nt)
      #pragma unroll
      for (int rr = 0; rr < 4; ++rr)
        pmax = fmaxf(pmax, s[nt][rr]);
    pmax = fmaxf(pmax, __shfl_xor(pmax, 16));
    pmax = fmaxf(pmax, __shfl_xor(pmax, 32));
    if (!__all(pmax - m_ <= 8.0f)) {  // defer-max (T13)
      float mn = fmaxf(m_, pmax);
      float al = __builtin_amdgcn_exp2f(m_ - mn);
      m_ = mn;
      l_ *= al;
      float av[4];
      #pragma unroll
      for (int rr = 0; rr < 4; ++rr) av[rr] = __shfl(al, 4 * g + rr, 16);
      #pragma unroll
      for (int nt = 0; nt < 4; ++nt)
        #pragma unroll
        for (int rr = 0; rr < 4; ++rr) o[nt][rr] *= av[rr];
    }
    float rs = 0.f;
    #pragma unroll
    for (int nt = 0; nt < 4; ++nt)
      #pragma unroll
      for (int rr = 0; rr < 4; ++rr) {
        float p = __builtin_amdgcn_exp2f(s[nt][rr] - m_);
        s[nt][rr] = p;
        rs += p;
      }
    rs += __shfl_xor(rs, 16);
    rs += __shfl_xor(rs, 32);
    l_ += rs;
    int pk[8];
    #pragma unroll
    for (int nt = 0; nt < 4; ++nt)
      #pragma unroll
      for (int h = 0; h < 2; ++h)
        asm("v_cvt_pk_bf16_f32 %0, %1, %2"
            : "=v"(pk[nt * 2 + h])
            : "v"(s[nt][2 * h]), "v"(s[nt][2 * h + 1]));

    // ---- O += P @ V : packed P is the A-fragment directly ----
    bf16x8 pa[2];
    {
      int4 t0; t0.x = pk[0]; t0.y = pk[1]; t0.z = pk[2]; t0.w = pk[3];
      int4 t1; t1.x = pk[4]; t1.y = pk[5]; t1.z = pk[6]; t1.w = pk[7];
      pa[0] = __builtin_bit_cast(bf16x8, t0);
      pa[1] = __builtin_bit_cast(bf16x8, t1);
    }
    __builtin_amdgcn_s_setprio(1);
    #pragma unroll
    for (int nt = 0; nt < 4; ++nt) {
      const int d = nt * 16 + r16;
      bf16x8 vb0 = *(const bf16x8*)&vT[cur][d * 64 + ((g ^ (d & 7)) * 8)];
      bf16x8 vb1 = *(const bf16x8*)&vT[cur][d * 64 + (((4 + g) ^ (d & 7)) * 8)];
      o[nt] = __builtin_amdgcn_mfma_f32_16x16x32_bf16(pa[0], vb0, o[nt], 0, 0, 0);
      o[nt] = __builtin_amdgcn_mfma_f32_16x16x32_bf16(pa[1], vb1, o[nt], 0, 0, 0);
    }
    __builtin_amdgcn_s_setprio(0);

    // ---- late half of async stage: write V^T[nxt] from regs ----
    if (pf) {
      const short* a0 = (const short*)&vn0;
      const short* a1 = (const short*)&vn1;
      #pragma unroll
      for (int j = 0; j < 8; ++j) {
        int d = vd0 + j;
        int val = ((int)(unsigned short)a0[j]) | (((int)(unsigned short)a1[j]) << 16);
        *(int*)&vT[nxt][d * 64 + ((vchunk ^ j) * 8) + velem] = val;
      }
    }
    __syncthreads();
  }

  // ---- epilogue: O /= l ----
  float lv[4];
  #pragma unroll
  for (int rr = 0; rr < 4; ++rr) lv[rr] = __shfl(l_, 4 * g + rr, 16);
  #pragma unroll
  for (int nt = 0; nt < 4; ++nt) {
    int d = nt * 16 + r16;
    #pragma unroll
    for (int rr = 0; rr < 4; ++rr) {
      int t = q0 + w * 16 + 4 * g + rr;
      O[(size_t)(b * T_ + t) * C_ + hh * 64 + d] = f2bf(o[nt][rr] / lv[rr]);
    }
  }
}

extern "C" void kernel_launch(void* const* d_in, const int* in_sizes, int n_in,
                              void* d_out, int out_size, void* d_ws, size_t ws_size,
                              hipStream_t stream) {
  const float* x     = (const float*)d_in[0];
  const float* w_qkv = (const float*)d_in[1];
  const float* b_qkv = (const float*)d_in[2];
  const float* w_out = (const float*)d_in[3];
  const float* b_out = (const float*)d_in[4];
  float* out = (float*)d_out;

  char* ws = (char*)d_ws;
  if (ws_size < (size_t)(40u << 20)) return;

  short* xb     = (short*)(ws);                        // 8 MiB  [4096][1024] bf16
  short* wqkvT  = (short*)(ws + ((size_t)8u << 20));   // 6 MiB  [3072][1024] bf16
  short* woutT  = (short*)(ws + ((size_t)14u << 20));  // 2 MiB  [1024][1024] bf16
  short* Qb     = (short*)(ws + ((size_t)16u << 20));  // 8 MiB  [B][H][T][D] (prescaled)
  short* Kb     = (short*)(ws + ((size_t)24u << 20));  // 8 MiB
  short* Vb     = (short*)(ws + ((size_t)32u << 20));  // 8 MiB
  short* attn_o = xb;  // xb dead after gemm_qkv

  cast_f32_bf16<<<4096, 256, 0, stream>>>(x, xb);
  transpose_cast<<<dim3(96, 32), dim3(32, 8), 0, stream>>>(w_qkv, wqkvT, 1024, 3072);
  transpose_cast<<<dim3(32, 32), dim3(32, 8), 0, stream>>>(w_out, woutT, 1024, 1024);
  gemm_qkv<<<dim3(32, 24), 256, 0, stream>>>(xb, wqkvT, b_qkv, Qb, Kb, Vb);
  attn_fwd<<<dim3(32, 32), 256, 0, stream>>>(Qb, Kb, Vb, attn_o);
  gemm_out<<<dim3(32, 8), 256, 0, stream>>>(attn_o, woutT, b_out, out);
}

// Round 6
// 125.076 us; speedup vs baseline: 2.1788x; 1.0734x over previous
//
#include <hip/hip_runtime.h>

#define B_ 2
#define T_ 2048
#define C_ 1024
#define H_ 16
#define D_ 64

using bf16x8 = __attribute__((ext_vector_type(8))) short;
using f32x4  = __attribute__((ext_vector_type(4))) float;

static __device__ __forceinline__ short f2bf(float f) {
  unsigned u = __builtin_bit_cast(unsigned, f);
  unsigned r = u + 0x7fffu + ((u >> 16) & 1u);
  return (short)(r >> 16);
}

#define GLD16(gp, lp) __builtin_amdgcn_global_load_lds( \
    (const __attribute__((address_space(1))) void*)(gp), \
    (__attribute__((address_space(3))) void*)(lp), 16, 0, 0)

// ---------------- cast f32 -> bf16 (vectorized) ----------------
__global__ __launch_bounds__(256) void cast_f32_bf16(const float* __restrict__ in,
                                                     short* __restrict__ out) {
  int i = blockIdx.x * blockDim.x + threadIdx.x;
  float4 v = ((const float4*)in)[i];
  short4 o;
  o.x = f2bf(v.x); o.y = f2bf(v.y); o.z = f2bf(v.z); o.w = f2bf(v.w);
  ((short4*)out)[i] = o;
}

// ---------------- transpose + cast: in [R][N] f32 -> out [N][R] bf16 ----------------
__global__ __launch_bounds__(256) void transpose_cast(const float* __restrict__ in,
                                                      short* __restrict__ out,
                                                      int R, int N) {
  __shared__ float tile[32][33];
  int bx = blockIdx.x * 32, by = blockIdx.y * 32;
  int tx = threadIdx.x, ty = threadIdx.y;
  #pragma unroll
  for (int j = 0; j < 32; j += 8)
    tile[ty + j][tx] = in[(size_t)(by + ty + j) * N + bx + tx];
  __syncthreads();
  #pragma unroll
  for (int j = 0; j < 32; j += 8)
    out[(size_t)(bx + ty + j) * R + by + tx] = f2bf(tile[tx][ty + j]);
}

// ---------------- GEMM: 128x128 tile, BK=64 (m97 geometry), global_load_lds ----------------
// LDS slot c of row holds global k-chunk c^(row&7); staged linearly by GLD16 with the
// XOR applied to the GLOBAL source address (both-sides rule). 32 MFMA between barriers.
__global__ __launch_bounds__(256) void gemm_qkv(const short* __restrict__ A,
                                                const short* __restrict__ Bt,
                                                const float* __restrict__ bias,
                                                short* __restrict__ Qo,
                                                short* __restrict__ Ko,
                                                short* __restrict__ Vo) {
  __shared__ short sA[128 * 64];
  __shared__ short sB[128 * 64];
  const int tid = threadIdx.x;
  const int w = tid >> 6, lane = tid & 63;
  const int wm = w >> 1, wn = w & 1;
  const int g = lane >> 4, r16 = lane & 15;
  const int m0 = blockIdx.x * 128, n0 = blockIdx.y * 128;
  const int krow = lane >> 3, kslot = lane & 7;

  f32x4 acc[4][4] = {};

  for (int k0 = 0; k0 < 1024; k0 += 64) {
    __syncthreads();
    #pragma unroll
    for (int p = 0; p < 4; ++p) {
      int rbase = w * 32 + p * 8;
      int row = rbase + krow;
      GLD16(&A[(size_t)(m0 + row) * 1024 + k0 + ((kslot ^ (row & 7)) * 8)], &sA[rbase * 64]);
      GLD16(&Bt[(size_t)(n0 + row) * 1024 + k0 + ((kslot ^ (row & 7)) * 8)], &sB[rbase * 64]);
    }
    __syncthreads();
    bf16x8 af[4][2], bf[4][2];
    #pragma unroll
    for (int mi = 0; mi < 4; ++mi) {
      int row = wm * 64 + mi * 16 + r16;
      #pragma unroll
      for (int c = 0; c < 2; ++c)
        af[mi][c] = *(const bf16x8*)&sA[row * 64 + (((c * 4 + g) ^ (row & 7)) * 8)];
    }
    #pragma unroll
    for (int ni = 0; ni < 4; ++ni) {
      int row = wn * 64 + ni * 16 + r16;
      #pragma unroll
      for (int c = 0; c < 2; ++c)
        bf[ni][c] = *(const bf16x8*)&sB[row * 64 + (((c * 4 + g) ^ (row & 7)) * 8)];
    }
    __builtin_amdgcn_s_setprio(1);
    #pragma unroll
    for (int mi = 0; mi < 4; ++mi)
      #pragma unroll
      for (int ni = 0; ni < 4; ++ni) {
        acc[mi][ni] = __builtin_amdgcn_mfma_f32_16x16x32_bf16(af[mi][0], bf[ni][0], acc[mi][ni], 0, 0, 0);
        acc[mi][ni] = __builtin_amdgcn_mfma_f32_16x16x32_bf16(af[mi][1], bf[ni][1], acc[mi][ni], 0, 0, 0);
      }
    __builtin_amdgcn_s_setprio(0);
  }

  #pragma unroll
  for (int mi = 0; mi < 4; ++mi) {
    #pragma unroll
    for (int ni = 0; ni < 4; ++ni) {
      int n = n0 + wn * 64 + ni * 16 + r16;
      float bv = bias[n];
      int which = n >> 10;
      int c = n & 1023;
      int hh = c >> 6, d = c & 63;
      short* dst = (which == 0) ? Qo : ((which == 1) ? Ko : Vo);
      float sc = (which == 0) ? 0.18033688f : 1.0f;  // 0.125 * log2(e) folded into Q
      #pragma unroll
      for (int rr = 0; rr < 4; ++rr) {
        int m = m0 + wm * 64 + mi * 16 + g * 4 + rr;
        int b = m >> 11, t = m & 2047;
        dst[(size_t)((b * H_ + hh) * T_ + t) * D_ + d] = f2bf((acc[mi][ni][rr] + bv) * sc);
      }
    }
  }
}

__global__ __launch_bounds__(256) void gemm_out(const short* __restrict__ A,
                                                const short* __restrict__ Bt,
                                                const float* __restrict__ bias,
                                                float* __restrict__ Out) {
  __shared__ short sA[128 * 64];
  __shared__ short sB[128 * 64];
  const int tid = threadIdx.x;
  const int w = tid >> 6, lane = tid & 63;
  const int wm = w >> 1, wn = w & 1;
  const int g = lane >> 4, r16 = lane & 15;
  const int m0 = blockIdx.x * 128, n0 = blockIdx.y * 128;
  const int krow = lane >> 3, kslot = lane & 7;

  f32x4 acc[4][4] = {};

  for (int k0 = 0; k0 < 1024; k0 += 64) {
    __syncthreads();
    #pragma unroll
    for (int p = 0; p < 4; ++p) {
      int rbase = w * 32 + p * 8;
      int row = rbase + krow;
      GLD16(&A[(size_t)(m0 + row) * 1024 + k0 + ((kslot ^ (row & 7)) * 8)], &sA[rbase * 64]);
      GLD16(&Bt[(size_t)(n0 + row) * 1024 + k0 + ((kslot ^ (row & 7)) * 8)], &sB[rbase * 64]);
    }
    __syncthreads();
    bf16x8 af[4][2], bf[4][2];
    #pragma unroll
    for (int mi = 0; mi < 4; ++mi) {
      int row = wm * 64 + mi * 16 + r16;
      #pragma unroll
      for (int c = 0; c < 2; ++c)
        af[mi][c] = *(const bf16x8*)&sA[row * 64 + (((c * 4 + g) ^ (row & 7)) * 8)];
    }
    #pragma unroll
    for (int ni = 0; ni < 4; ++ni) {
      int row = wn * 64 + ni * 16 + r16;
      #pragma unroll
      for (int c = 0; c < 2; ++c)
        bf[ni][c] = *(const bf16x8*)&sB[row * 64 + (((c * 4 + g) ^ (row & 7)) * 8)];
    }
    __builtin_amdgcn_s_setprio(1);
    #pragma unroll
    for (int mi = 0; mi < 4; ++mi)
      #pragma unroll
      for (int ni = 0; ni < 4; ++ni) {
        acc[mi][ni] = __builtin_amdgcn_mfma_f32_16x16x32_bf16(af[mi][0], bf[ni][0], acc[mi][ni], 0, 0, 0);
        acc[mi][ni] = __builtin_amdgcn_mfma_f32_16x16x32_bf16(af[mi][1], bf[ni][1], acc[mi][ni], 0, 0, 0);
      }
    __builtin_amdgcn_s_setprio(0);
  }

  #pragma unroll
  for (int mi = 0; mi < 4; ++mi) {
    #pragma unroll
    for (int ni = 0; ni < 4; ++ni) {
      int n = n0 + wn * 64 + ni * 16 + r16;
      float bv = bias[n];
      #pragma unroll
      for (int rr = 0; rr < 4; ++rr) {
        int m = m0 + wm * 64 + mi * 16 + g * 4 + rr;
        Out[(size_t)m * 1024 + n] = acc[mi][ni][rr] + bv;
      }
    }
  }
}

// ---------------- flash attention: counted-vmcnt pipeline (T4), K 2-ahead, V 1-ahead ----------
// grid (bh=32, 32); qi = 31 - blockIdx.y (LPT). Block = 4 waves x 16 q-rows, KVBLK=64.
// sK triple-buffered: K(kt+2) GLD16s stay IN FLIGHT across the barrier (vmcnt(2), never 0
// in steady state). V reg-staged 1-ahead (issue early / ds_write late, T14).
__global__ __launch_bounds__(256, 4) void attn_fwd(const short* __restrict__ Q,
                                                   const short* __restrict__ K,
                                                   const short* __restrict__ V,
                                                   short* __restrict__ O) {
  __shared__ short sK[3][64 * 64];   // [key][d], chunk c holds d-chunk c^(key&7)
  __shared__ short vT[2][64 * 64];   // [d][slot], slot = pi(key); chunk c' holds c'^(d&7)

  const int tid = threadIdx.x;
  const int w = tid >> 6, lane = tid & 63;
  const int g = lane >> 4, r16 = lane & 15;
  const int bh = blockIdx.x;
  const int b = bh >> 4, hh = bh & 15;
  const int qi = 31 - (int)blockIdx.y;  // LPT: heavy first
  const int q0 = qi * 64;

  const short* Qh = Q + (size_t)bh * T_ * D_;
  const short* Kh = K + (size_t)bh * T_ * D_;
  const short* Vh = V + (size_t)bh * T_ * D_;

  const int krow_in_wave = lane >> 3;
  const int kslot = lane & 7;
  // V slot permutation: slot = 32a + 8c + 4b + 2d + e for key = 32a+16b+4c+2d+e
  const int kp = tid & 31;
  const int vd0 = (tid >> 5) * 8;
  const int vchunk = (kp >> 4) * 4 + ((kp & 7) >> 1);
  const int velem  = ((kp >> 3) & 1) * 4 + 2 * (kp & 1);

  const int qrow_a = q0 + w * 16 + r16;
  bf16x8 qf[2];
  qf[0] = *(const bf16x8*)&Qh[(size_t)qrow_a * 64 + g * 8];
  qf[1] = *(const bf16x8*)&Qh[(size_t)qrow_a * 64 + 32 + g * 8];

  f32x4 o[4] = {};
  float m_ = -1e30f, l_ = 0.f;

  const int nkt = qi + 1;

  // ---- prologue: V(0) regs; K(0), K(1) GLD16 ----
  {
    int4 v0 = *(const int4*)&Vh[(size_t)(2 * kp) * 64 + vd0];
    int4 v1 = *(const int4*)&Vh[(size_t)(2 * kp + 1) * 64 + vd0];
    #pragma unroll
    for (int p = 0; p < 2; ++p) {
      int row = w * 16 + p * 8 + krow_in_wave;
      GLD16(&Kh[(size_t)row * 64 + ((kslot ^ (row & 7)) * 8)], &sK[0][(w * 16 + p * 8) * 64]);
    }
    if (nkt > 1) {
      #pragma unroll
      for (int p = 0; p < 2; ++p) {
        int row = w * 16 + p * 8 + krow_in_wave;
        GLD16(&Kh[(size_t)(64 + row) * 64 + ((kslot ^ (row & 7)) * 8)],
              &sK[1][(w * 16 + p * 8) * 64]);
      }
    }
    const short* a0 = (const short*)&v0;
    const short* a1 = (const short*)&v1;
    #pragma unroll
    for (int j = 0; j < 8; ++j) {
      int d = vd0 + j;  // d&7 == j
      int val = ((int)(unsigned short)a0[j]) | (((int)(unsigned short)a1[j]) << 16);
      *(int*)&vT[0][d * 64 + ((vchunk ^ j) * 8) + velem] = val;
    }
    if (nkt > 1) asm volatile("s_waitcnt vmcnt(2)" ::: "memory");
    else         asm volatile("s_waitcnt vmcnt(0)" ::: "memory");
    asm volatile("s_waitcnt lgkmcnt(0)" ::: "memory");
    __builtin_amdgcn_sched_barrier(0);
    __builtin_amdgcn_s_barrier();
    __builtin_amdgcn_sched_barrier(0);
  }

  for (int kt = 0; kt < nkt; ++kt) {
    const int cur3 = kt % 3;
    const int curv = kt & 1;
    const bool pf1 = (kt + 1 < nkt);
    const bool pf2 = (kt + 2 < nkt);

    // ---- issue next V (regs) and next-next K (GLD16) early ----
    int4 vn0, vn1;
    if (pf1) {
      const int k1 = (kt + 1) * 64;
      vn0 = *(const int4*)&Vh[(size_t)(k1 + 2 * kp) * 64 + vd0];
      vn1 = *(const int4*)&Vh[(size_t)(k1 + 2 * kp + 1) * 64 + vd0];
    }
    if (pf2) {
      const int k2 = (kt + 2) * 64;
      const int nb = (kt + 2) % 3;
      #pragma unroll
      for (int p = 0; p < 2; ++p) {
        int row = w * 16 + p * 8 + krow_in_wave;
        GLD16(&Kh[(size_t)(k2 + row) * 64 + ((kslot ^ (row & 7)) * 8)],
              &sK[nb][(w * 16 + p * 8) * 64]);
      }
    }
    __builtin_amdgcn_sched_barrier(0);  // pin issue cluster before compute

    // ---- S^T = K Q^T : lane holds S[key = nt*16+4g+rr][q = r16] ----
    f32x4 s[4] = {};
    __builtin_amdgcn_s_setprio(1);
    #pragma unroll
    for (int nt = 0; nt < 4; ++nt) {
      const int row = nt * 16 + r16;
      const int sw8 = r16 & 7;
      bf16x8 kf0 = *(const bf16x8*)&sK[cur3][row * 64 + ((g ^ sw8) * 8)];
      bf16x8 kf1 = *(const bf16x8*)&sK[cur3][row * 64 + (((4 + g) ^ sw8) * 8)];
      s[nt] = __builtin_amdgcn_mfma_f32_16x16x32_bf16(kf0, qf[0], s[nt], 0, 0, 0);
      s[nt] = __builtin_amdgcn_mfma_f32_16x16x32_bf16(kf1, qf[1], s[nt], 0, 0, 0);
    }
    __builtin_amdgcn_s_setprio(0);

    // ---- online softmax (log2 domain; Q prescaled) ----
    if (kt == nkt - 1) {  // diagonal tile
      const int qrow = w * 16 + r16;
      #pragma unroll
      for (int nt = 0; nt < 4; ++nt)
        #pragma unroll
        for (int rr = 0; rr < 4; ++rr)
          if (nt * 16 + 4 * g + rr > qrow) s[nt][rr] = -1e30f;
    }
    float pmax = s[0][0];
    #pragma unroll
    for (int nt = 0; nt < 4; ++nt)
      #pragma unroll
      for (int rr = 0; rr < 4; ++rr)
        pmax = fmaxf(pmax, s[nt][rr]);
    pmax = fmaxf(pmax, __shfl_xor(pmax, 16));
    pmax = fmaxf(pmax, __shfl_xor(pmax, 32));
    if (!__all(pmax - m_ <= 8.0f)) {  // defer-max (T13)
      float mn = fmaxf(m_, pmax);
      float al = __builtin_amdgcn_exp2f(m_ - mn);
      m_ = mn;
      l_ *= al;
      float av[4];
      #pragma unroll
      for (int rr = 0; rr < 4; ++rr) av[rr] = __shfl(al, 4 * g + rr, 16);
      #pragma unroll
      for (int nt = 0; nt < 4; ++nt)
        #pragma unroll
        for (int rr = 0; rr < 4; ++rr) o[nt][rr] *= av[rr];
    }
    float rs = 0.f;
    #pragma unroll
    for (int nt = 0; nt < 4; ++nt)
      #pragma unroll
      for (int rr = 0; rr < 4; ++rr) {
        float p = __builtin_amdgcn_exp2f(s[nt][rr] - m_);
        s[nt][rr] = p;
        rs += p;
      }
    rs += __shfl_xor(rs, 16);
    rs += __shfl_xor(rs, 32);
    l_ += rs;
    int pk[8];
    #pragma unroll
    for (int nt = 0; nt < 4; ++nt)
      #pragma unroll
      for (int h = 0; h < 2; ++h)
        asm("v_cvt_pk_bf16_f32 %0, %1, %2"
            : "=v"(pk[nt * 2 + h])
            : "v"(s[nt][2 * h]), "v"(s[nt][2 * h + 1]));

    // ---- O += P @ V : packed P is the A-fragment directly ----
    bf16x8 pa[2];
    {
      int4 t0; t0.x = pk[0]; t0.y = pk[1]; t0.z = pk[2]; t0.w = pk[3];
      int4 t1; t1.x = pk[4]; t1.y = pk[5]; t1.z = pk[6]; t1.w = pk[7];
      pa[0] = __builtin_bit_cast(bf16x8, t0);
      pa[1] = __builtin_bit_cast(bf16x8, t1);
    }
    __builtin_amdgcn_s_setprio(1);
    #pragma unroll
    for (int nt = 0; nt < 4; ++nt) {
      const int d = nt * 16 + r16;
      bf16x8 vb0 = *(const bf16x8*)&vT[curv][d * 64 + ((g ^ (d & 7)) * 8)];
      bf16x8 vb1 = *(const bf16x8*)&vT[curv][d * 64 + (((4 + g) ^ (d & 7)) * 8)];
      o[nt] = __builtin_amdgcn_mfma_f32_16x16x32_bf16(pa[0], vb0, o[nt], 0, 0, 0);
      o[nt] = __builtin_amdgcn_mfma_f32_16x16x32_bf16(pa[1], vb1, o[nt], 0, 0, 0);
    }
    __builtin_amdgcn_s_setprio(0);

    // ---- late stage-write of V(kt+1); counted-vmcnt barrier ----
    if (pf1) {
      const short* a0 = (const short*)&vn0;
      const short* a1 = (const short*)&vn1;
      #pragma unroll
      for (int j = 0; j < 8; ++j) {
        int d = vd0 + j;
        int val = ((int)(unsigned short)a0[j]) | (((int)(unsigned short)a1[j]) << 16);
        *(int*)&vT[curv ^ 1][d * 64 + ((vchunk ^ j) * 8) + velem] = val;
      }
      // Drain K(kt+1) (+V regs already consumed); leave K(kt+2)'s 2 loads in flight.
      if (pf2) asm volatile("s_waitcnt vmcnt(2)" ::: "memory");
      else     asm volatile("s_waitcnt vmcnt(0)" ::: "memory");
      asm volatile("s_waitcnt lgkmcnt(0)" ::: "memory");
      __builtin_amdgcn_sched_barrier(0);
      __builtin_amdgcn_s_barrier();
      __builtin_amdgcn_sched_barrier(0);
    }
  }

  // ---- epilogue: O /= l ----
  float lv[4];
  #pragma unroll
  for (int rr = 0; rr < 4; ++rr) lv[rr] = __shfl(l_, 4 * g + rr, 16);
  #pragma unroll
  for (int nt = 0; nt < 4; ++nt) {
    int d = nt * 16 + r16;
    #pragma unroll
    for (int rr = 0; rr < 4; ++rr) {
      int t = q0 + w * 16 + 4 * g + rr;
      O[(size_t)(b * T_ + t) * C_ + hh * 64 + d] = f2bf(o[nt][rr] / lv[rr]);
    }
  }
}

extern "C" void kernel_launch(void* const* d_in, const int* in_sizes, int n_in,
                              void* d_out, int out_size, void* d_ws, size_t ws_size,
                              hipStream_t stream) {
  const float* x     = (const float*)d_in[0];
  const float* w_qkv = (const float*)d_in[1];
  const float* b_qkv = (const float*)d_in[2];
  const float* w_out = (const float*)d_in[3];
  const float* b_out = (const float*)d_in[4];
  float* out = (float*)d_out;

  char* ws = (char*)d_ws;
  if (ws_size < (size_t)(40u << 20)) return;

  short* xb     = (short*)(ws);                        // 8 MiB  [4096][1024] bf16
  short* wqkvT  = (short*)(ws + ((size_t)8u << 20));   // 6 MiB  [3072][1024] bf16
  short* woutT  = (short*)(ws + ((size_t)14u << 20));  // 2 MiB  [1024][1024] bf16
  short* Qb     = (short*)(ws + ((size_t)16u << 20));  // 8 MiB  [B][H][T][D] (prescaled)
  short* Kb     = (short*)(ws + ((size_t)24u << 20));  // 8 MiB
  short* Vb     = (short*)(ws + ((size_t)32u << 20));  // 8 MiB
  short* attn_o = xb;  // xb dead after gemm_qkv

  cast_f32_bf16<<<4096, 256, 0, stream>>>(x, xb);
  transpose_cast<<<dim3(96, 32), dim3(32, 8), 0, stream>>>(w_qkv, wqkvT, 1024, 3072);
  transpose_cast<<<dim3(32, 32), dim3(32, 8), 0, stream>>>(w_out, woutT, 1024, 1024);
  gemm_qkv<<<dim3(32, 24), 256, 0, stream>>>(xb, wqkvT, b_qkv, Qb, Kb, Vb);
  attn_fwd<<<dim3(32, 32), 256, 0, stream>>>(Qb, Kb, Vb, attn_o);
  gemm_out<<<dim3(32, 8), 256, 0, stream>>>(attn_o, woutT, b_out, out);
}